// Round 13
// baseline (233.614 us; speedup 1.0000x reference)
//
#include <hip/hip_runtime.h>

typedef unsigned short u16;
typedef __attribute__((ext_vector_type(8))) short bf16x8;   // 8 bf16 in 4 VGPRs (MFMA A/B frag)
typedef __attribute__((ext_vector_type(4))) float f32x4;    // MFMA C/D frag

#define SS 2048
#define EE 1024
#define HH 16
#define DD 64

__device__ __forceinline__ float b2f(u16 u) {
  union { unsigned int i; float f; } v; v.i = ((unsigned int)u) << 16; return v.f;
}
__device__ __forceinline__ u16 f2b(float f) {
  union { float f; unsigned int i; } v; v.f = f;
  unsigned int i = v.i;
  return (u16)((i + 0x7FFFu + ((i >> 16) & 1u)) >> 16);  // RNE
}
__device__ __forceinline__ unsigned int cvt_pk_bf16(float lo, float hi) {
  unsigned int r;
  asm("v_cvt_pk_bf16_f32 %0, %1, %2" : "=v"(r) : "v"(lo), "v"(hi));  // RNE pack, low=lo
  return r;
}

// async global->LDS, 16B per lane (m97 pattern; LDS dest = wave-uniform base + lane*16)
#define GLD16(g, l)                                                         \
  __builtin_amdgcn_global_load_lds(                                         \
      (const __attribute__((address_space(1))) unsigned int*)(g),           \
      (__attribute__((address_space(3))) unsigned int*)(l), 16, 0, 0)

// ---------------- fused prep: qkv_w cvt | trig table | LayerNorm ----------------
// blocks [0,3072): cvt qkv_w -> bf16; [3072,3076): cos/sin table; [3076,7172): LN rows
__global__ __launch_bounds__(256) void k_prep(const float* __restrict__ qkv_w,
                                              u16* __restrict__ wq_b,
                                              const float* __restrict__ inv_freq,
                                              float2* __restrict__ cs,
                                              const float* __restrict__ x,
                                              const float* __restrict__ lw,
                                              const float* __restrict__ lb,
                                              u16* __restrict__ xn) {
  const int bx = blockIdx.x, t = threadIdx.x;
  if (bx < 3072) {
    const int i = bx * 256 + t;
    float4 v = ((const float4*)qkv_w)[i];
    ushort4 o;
    o.x = f2b(v.x); o.y = f2b(v.y); o.z = f2b(v.z); o.w = f2b(v.w);
    ((ushort4*)wq_b)[i] = o;
    return;
  }
  if (bx < 3076) {
    const int i = (bx - 3072) * 256 + t;
    float th = 2048.0f * inv_freq[i];
    cs[i] = make_float2(cosf(th), sinf(th));
    return;
  }
  const int row = bx - 3076;
  float4 v = ((const float4*)(x + (size_t)row * EE))[t];
  float f0 = v.x, f1 = v.y, f2 = v.z, f3 = v.w;
  float s = f0 + f1 + f2 + f3;
  float ss = f0 * f0 + f1 * f1 + f2 * f2 + f3 * f3;
  for (int o = 1; o < 64; o <<= 1) { s += __shfl_xor(s, o); ss += __shfl_xor(ss, o); }
  __shared__ float red[8];
  int w = t >> 6;
  if ((t & 63) == 0) { red[w] = s; red[4 + w] = ss; }
  __syncthreads();
  s = red[0] + red[1] + red[2] + red[3];
  ss = red[4] + red[5] + red[6] + red[7];
  float mu = s * (1.0f / 1024.0f);
  float var = ss * (1.0f / 1024.0f) - mu * mu;
  float rstd = rsqrtf(var + 1e-5f);
  float4 wv = ((const float4*)lw)[t];
  float4 bv = ((const float4*)lb)[t];
  ushort4 o;
  o.x = f2b((f0 - mu) * rstd * wv.x + bv.x);
  o.y = f2b((f1 - mu) * rstd * wv.y + bv.y);
  o.z = f2b((f2 - mu) * rstd * wv.z + bv.z);
  o.w = f2b((f3 - mu) * rstd * wv.w + bv.w);
  ((ushort4*)(xn + (size_t)row * EE))[t] = o;
}

// ---- MFMA GEMM  C[M,N] = A[M,K] * W[N,K]^T + bias (bf16 A and W) ----
// m97 structure: 128x128 tile, BK=32, linear LDS, global_load_lds x16.
// V-direct epilogue (FIXED): V col-blocks (n0 >= 2048) stage their tile through
// a padded LDS transpose buffer (like the old k_vtrans) and write V^T with
// 128 B-contiguous per-thread segments — coalesced, unlike round 12's scatter.
__global__ __launch_bounds__(256) void k_gemm_b(const u16* __restrict__ A,
                                                const u16* __restrict__ W,
                                                const float* __restrict__ bias,
                                                u16* __restrict__ C,
                                                u16* __restrict__ VT,
                                                int M, int N, int K) {
  __shared__ __align__(16) u16 As[128 * 32];
  __shared__ __align__(16) u16 Ws[128 * 32];
  __shared__ __align__(16) u16 Tt[128 * 136];   // V^T staging (epilogue only)
  const int t = threadIdx.x;
  const int m0 = blockIdx.y * 128, n0 = blockIdx.x * 128;
  const int lane = t & 63, w = t >> 6, quad = lane >> 4, l15 = lane & 15;
  const int wm = (w & 1) * 64, wn = (w >> 1) * 64;

  f32x4 zero4 = {0.f, 0.f, 0.f, 0.f};
  f32x4 acc[4][4];
  for (int mi = 0; mi < 4; mi++)
    for (int ni = 0; ni < 4; ni++) acc[mi][ni] = zero4;

  const u16* Ag = A + (size_t)(m0 + (t >> 2)) * K + (t & 3) * 8;
  const u16* Wg = W + (size_t)(n0 + (t >> 2)) * K + (t & 3) * 8;
  const size_t rowskip = (size_t)64 * K;

  for (int k0 = 0; k0 < K; k0 += 32) {
    GLD16(Ag + k0, As + t * 8);
    GLD16(Ag + rowskip + k0, As + 2048 + t * 8);
    GLD16(Wg + k0, Ws + t * 8);
    GLD16(Wg + rowskip + k0, Ws + 2048 + t * 8);
    __syncthreads();
    bf16x8 af[4], wf[4];
#pragma unroll
    for (int i = 0; i < 4; i++) {
      af[i] = *(const bf16x8*)(As + (wm + i * 16 + l15) * 32 + quad * 8);
      wf[i] = *(const bf16x8*)(Ws + (wn + i * 16 + l15) * 32 + quad * 8);
    }
#pragma unroll
    for (int mi = 0; mi < 4; mi++)
#pragma unroll
      for (int ni = 0; ni < 4; ni++)
        acc[mi][ni] = __builtin_amdgcn_mfma_f32_16x16x32_bf16(af[mi], wf[ni], acc[mi][ni], 0, 0, 0);
    __syncthreads();
  }
  if (n0 < 2048) {  // Q/K sections: row-major write to qkv (block-uniform branch)
    for (int mi = 0; mi < 4; mi++)
      for (int ni = 0; ni < 4; ni++) {
        int col = n0 + wn + ni * 16 + l15;
        float bb = bias[col];
        for (int r = 0; r < 4; r++) {
          int grow = m0 + wm + mi * 16 + quad * 4 + r;
          C[(size_t)grow * N + col] = f2b(acc[mi][ni][r] + bb);
        }
      }
  } else {
    // V section: LDS transpose (Tt[col][s], pad 136 -> 2-way banks = free) ...
    for (int mi = 0; mi < 4; mi++)
      for (int ni = 0; ni < 4; ni++) {
        int cn = wn + ni * 16 + l15;               // in-tile col 0..127
        int sIn = wm + mi * 16 + quad * 4;         // in-tile row (4 consecutive)
        float bb = bias[n0 + cn];
        ushort4 o;
        o.x = f2b(acc[mi][ni][0] + bb);
        o.y = f2b(acc[mi][ni][1] + bb);
        o.z = f2b(acc[mi][ni][2] + bb);
        o.w = f2b(acc[mi][ni][3] + bb);
        *(ushort4*)(Tt + cn * 136 + sIn) = o;
      }
    __syncthreads();
    // ... then coalesced V^T write: thread t owns col t>>1, half t&1 -> 128 B run
    const int cn = t >> 1, half = t & 1;
    const int h = (n0 - 2048 + cn) >> 6, d = cn & 63;
    const int bb_ = m0 >> 11, s0 = (m0 & 2047) + half * 64;
    u16* dst = VT + ((size_t)((bb_ * 16 + h) * 64 + d)) * SS + s0;
    const u16* srcT = Tt + cn * 136 + half * 64;
#pragma unroll
    for (int it = 0; it < 8; it++)
      *(bf16x8*)(dst + it * 8) = *(const bf16x8*)(srcT + it * 8);
  }
}

// ---- MFMA GEMM with fp32 W (converted in-flight; replaces k_cvt + bf16 gemm_f) ----
// 64x128 tile: As via GLD16; W fp32 reg-staged -> cvt_pk -> linear b128 ds_write
__global__ __launch_bounds__(256) void k_gemm_fw(const u16* __restrict__ A,
                                                 const float* __restrict__ W,
                                                 const float* __restrict__ bias,
                                                 float* __restrict__ C,
                                                 int M, int N, int K) {
  __shared__ __align__(16) u16 As[64 * 32];
  __shared__ __align__(16) u16 Ws[128 * 32];
  const int t = threadIdx.x;
  const int m0 = blockIdx.y * 64, n0 = blockIdx.x * 128;
  const int lane = t & 63, w = t >> 6, quad = lane >> 4, l15 = lane & 15;
  const int wm = (w & 1) * 32, wn = (w >> 1) * 64;

  f32x4 zero4 = {0.f, 0.f, 0.f, 0.f};
  f32x4 acc[2][4];
  for (int mi = 0; mi < 2; mi++)
    for (int ni = 0; ni < 4; ni++) acc[mi][ni] = zero4;

  const u16* Ag = A + (size_t)(m0 + (t >> 2)) * K + (t & 3) * 8;
  const float* Wg0 = W + (size_t)(n0 + (t >> 2)) * K + (t & 3) * 8;
  const float* Wg1 = Wg0 + (size_t)64 * K;

  for (int k0 = 0; k0 < K; k0 += 32) {
    GLD16(Ag + k0, As + t * 8);
    float4 wa = *(const float4*)(Wg0 + k0);
    float4 wb = *(const float4*)(Wg0 + k0 + 4);
    float4 wc = *(const float4*)(Wg1 + k0);
    float4 wd = *(const float4*)(Wg1 + k0 + 4);
    union { unsigned int u[4]; bf16x8 v8; } p0, p1;
    p0.u[0] = cvt_pk_bf16(wa.x, wa.y); p0.u[1] = cvt_pk_bf16(wa.z, wa.w);
    p0.u[2] = cvt_pk_bf16(wb.x, wb.y); p0.u[3] = cvt_pk_bf16(wb.z, wb.w);
    p1.u[0] = cvt_pk_bf16(wc.x, wc.y); p1.u[1] = cvt_pk_bf16(wc.z, wc.w);
    p1.u[2] = cvt_pk_bf16(wd.x, wd.y); p1.u[3] = cvt_pk_bf16(wd.z, wd.w);
    *(bf16x8*)(Ws + t * 8) = p0.v8;         // rows 0..63, linear (conflict-free)
    *(bf16x8*)(Ws + 2048 + t * 8) = p1.v8;  // rows 64..127
    __syncthreads();
    bf16x8 af[2], wf[4];
#pragma unroll
    for (int i = 0; i < 2; i++)
      af[i] = *(const bf16x8*)(As + (wm + i * 16 + l15) * 32 + quad * 8);
#pragma unroll
    for (int i = 0; i < 4; i++)
      wf[i] = *(const bf16x8*)(Ws + (wn + i * 16 + l15) * 32 + quad * 8);
#pragma unroll
    for (int mi = 0; mi < 2; mi++)
#pragma unroll
      for (int ni = 0; ni < 4; ni++)
        acc[mi][ni] = __builtin_amdgcn_mfma_f32_16x16x32_bf16(af[mi], wf[ni], acc[mi][ni], 0, 0, 0);
    __syncthreads();
  }
  for (int mi = 0; mi < 2; mi++)
    for (int ni = 0; ni < 4; ni++) {
      int col = n0 + wn + ni * 16 + l15;
      float bb = bias[col];
      for (int r = 0; r < 4; r++) {
        int grow = m0 + wm + mi * 16 + quad * 4 + r;
        C[(size_t)grow * N + col] = acc[mi][ni][r] + bb;
      }
    }
}

// ------ rotate (table) + per-head l2norm + qknorm scale (pure; vtrans fused into gemm) ------
__global__ __launch_bounds__(256) void k_rotv(u16* __restrict__ qkv,
                                              const float2* __restrict__ cs_tab,
                                              const float* __restrict__ scale_p) {
  __shared__ float qf[1024];
  __shared__ float kf[1024];
  const int row = blockIdx.x, t = threadIdx.x;
  u16* qr = qkv + (size_t)row * 3072;
  u16* kr = qr + 1024;
  ushort4 qv = ((const ushort4*)qr)[t];
  ushort4 kv = ((const ushort4*)kr)[t];
  *(float4*)(qf + 4 * t) = make_float4(b2f(qv.x), b2f(qv.y), b2f(qv.z), b2f(qv.w));
  *(float4*)(kf + 4 * t) = make_float4(b2f(kv.x), b2f(kv.y), b2f(kv.z), b2f(kv.w));
  __syncthreads();
  const float scale = scale_p[0];
  float rq[4], rk[4];
#pragma unroll
  for (int u = 0; u < 4; u++) {
    int j = 4 * t + u;
    float2 cs = cs_tab[j];
    float qrot = (j < 512) ? -qf[2 * j + 1] : qf[2 * (j - 512)];
    float krot = (j < 512) ? -kf[2 * j + 1] : kf[2 * (j - 512)];
    rq[u] = qf[j] * cs.x + qrot * cs.y;
    rk[u] = kf[j] * cs.x + krot * cs.y;
  }
  float ssq = rq[0] * rq[0] + rq[1] * rq[1] + rq[2] * rq[2] + rq[3] * rq[3];
  float ssk = rk[0] * rk[0] + rk[1] * rk[1] + rk[2] * rk[2] + rk[3] * rk[3];
  for (int o = 1; o < 16; o <<= 1) { ssq += __shfl_xor(ssq, o); ssk += __shfl_xor(ssk, o); }
  float qs = scale / fmaxf(sqrtf(ssq), 1e-12f);
  float ks = scale / fmaxf(sqrtf(ssk), 1e-12f);
  ushort4 qo, ko;
  qo.x = f2b(rq[0] * qs); qo.y = f2b(rq[1] * qs); qo.z = f2b(rq[2] * qs); qo.w = f2b(rq[3] * qs);
  ko.x = f2b(rk[0] * ks); ko.y = f2b(rk[1] * ks); ko.z = f2b(rk[2] * ks); ko.w = f2b(rk[3] * ks);
  ((ushort4*)qr)[t] = qo;
  ((ushort4*)kr)[t] = ko;
}

// ---------------- causal flash attention (MFMA, swapped QK^T, in-register P) ----------------
// QBLK=128 via 8 warps; KBLK=128. Grid (32,16): bh = blockIdx.x, qt = y<8 ? y : 23-y
// (co-resident block pairs f,f+256 share bh -> K/V L2-resident; qt sums to 15).
// SWAPPED QK^T -> lane-local softmax (+2 shfl_xor); in-register P via cross-quad shfl.
// defer-max (T13, THR=8) and s_setprio(1) around MFMA clusters (T5).
__global__ __launch_bounds__(512, 4) void k_attn(const u16* __restrict__ qkv,
                                                 const u16* __restrict__ vt,
                                                 u16* __restrict__ out) {
  __shared__ __align__(16) u16 Kt[2][128 * 72];    // K rows (d=0..63 + pad)
  __shared__ __align__(16) u16 Vt[2][64 * 136];    // V^T rows d, k=0..127 + pad
  const int bh = blockIdx.x;
  const int y = blockIdx.y;
  const int qt = (y < 8) ? y : 23 - y;             // 128-row q-tile, 0..15
  const int b = bh >> 4, h = bh & 15;
  const int t = threadIdx.x, w = t >> 6, lane = t & 63, quad = lane >> 4, l15 = lane & 15;
  const int krow = t >> 2, kq = (t & 3) * 16;  // K staging: row 0..127, 16-u16 quarter
  const int dr = t >> 3, kc8 = t & 7;          // V staging: d-row 0..63, 16-k eighth
  const int srcl = (lane & 48) + ((lane >> 4) << 2);  // 20*quad: state-holder base lane
  const int qA = ((lane >> 4) & 1) * 32 + l15;        // P-exchange src lane
  const int qB = qA + 16;
  const bool hiN = (quad >> 1) & 1;
  const u16* kn = qkv + 1024;
  f32x4 zero4 = {0.f, 0.f, 0.f, 0.f};
  const int q0 = qt * 128;

  bf16x8 qf[2];
  {
    const u16* qrow = qkv + (size_t)(b * SS + q0 + 16 * w + l15) * 3072 + h * DD;
    qf[0] = *(const bf16x8*)(qrow + quad * 8);
    qf[1] = *(const bf16x8*)(qrow + 32 + quad * 8);
  }
  f32x4 oacc[4];
  for (int n = 0; n < 4; n++) oacc[n] = zero4;
  float m_i = -1e30f, l_i = 0.f;   // per-lane: state for q-row 16w+l15

  bf16x8 kv[2], vv[2];
  // prologue: load & stage tile kt=0 into buf 0
  {
    const u16* krg = kn + (size_t)(b * SS + krow) * 3072 + h * DD + kq;
    kv[0] = *(const bf16x8*)(krg);
    kv[1] = *(const bf16x8*)(krg + 8);
    const u16* vrg = vt + (size_t)(bh * DD + dr) * SS + kc8 * 16;
    vv[0] = *(const bf16x8*)(vrg);
    vv[1] = *(const bf16x8*)(vrg + 8);
  }
  *(bf16x8*)(Kt[0] + krow * 72 + kq) = kv[0];
  *(bf16x8*)(Kt[0] + krow * 72 + kq + 8) = kv[1];
  *(bf16x8*)(Vt[0] + dr * 136 + kc8 * 16) = vv[0];
  *(bf16x8*)(Vt[0] + dr * 136 + kc8 * 16 + 8) = vv[1];
  __syncthreads();
  int cur = 0;

  for (int kt = 0; kt <= qt; kt++) {
    if (kt < qt) {  // prefetch next tile into regs; staged into buf^1 below
      const int k0n = (kt + 1) * 128;
      const u16* krg = kn + (size_t)(b * SS + k0n + krow) * 3072 + h * DD + kq;
      kv[0] = *(const bf16x8*)(krg);
      kv[1] = *(const bf16x8*)(krg + 8);
      const u16* vrg = vt + (size_t)(bh * DD + dr) * SS + k0n + kc8 * 16;
      vv[0] = *(const bf16x8*)(vrg);
      vv[1] = *(const bf16x8*)(vrg + 8);
    }
    const u16* Kc = Kt[cur];
    const u16* Vc = Vt[cur];
    // ---- swapped QK^T: A = K-group (16 k-rows), B = Q ----
    f32x4 sacc[8];
    __builtin_amdgcn_s_setprio(1);
#pragma unroll
    for (int n = 0; n < 8; n++) {
      sacc[n] = zero4;
#pragma unroll
      for (int c = 0; c < 2; c++) {
        bf16x8 kfrag = *(const bf16x8*)(Kc + (n * 16 + l15) * 72 + c * 32 + quad * 8);
        sacc[n] = __builtin_amdgcn_mfma_f32_16x16x32_bf16(kfrag, qf[c], sacc[n], 0, 0, 0);
      }
    }
    __builtin_amdgcn_s_setprio(0);
    if (kt == qt) {  // diagonal: mask k > q-row-in-tile; k = 16n+4quad+r, q = 16w+l15
      const int qrow = 16 * w + l15, kbase = 4 * quad;
#pragma unroll
      for (int n = 0; n < 8; n++)
#pragma unroll
        for (int r = 0; r < 4; r++)
          if (16 * n + kbase + r > qrow) sacc[n][r] = -1e30f;
    }
    // ---- lane-local softmax for q-row 16w+l15, defer-max (THR=8) ----
    float mx = -1e30f;
#pragma unroll
    for (int n = 0; n < 8; n++)
#pragma unroll
      for (int r = 0; r < 4; r++) mx = fmaxf(mx, sacc[n][r]);
    mx = fmaxf(mx, __shfl_xor(mx, 16));
    mx = fmaxf(mx, __shfl_xor(mx, 32));
    const bool need = !__all(mx - m_i <= 8.0f);   // wave-uniform
    float al = 1.0f;
    if (need) {
      float mn = fmaxf(m_i, mx);
      al = __expf(m_i - mn);
      m_i = mn;
    }
    float rs = 0.f;
#pragma unroll
    for (int n = 0; n < 8; n++)
#pragma unroll
      for (int r = 0; r < 4; r++) {
        float p = __expf(sacc[n][r] - m_i);
        sacc[n][r] = p;
        rs += p;
      }
    rs += __shfl_xor(rs, 16);
    rs += __shfl_xor(rs, 32);
    l_i = al * l_i + rs;
    if (need) {  // rescale O (row q = quad*4+r; state at lane 20*quad+r)
      float alr[4];
#pragma unroll
      for (int r = 0; r < 4; r++) alr[r] = __shfl(al, srcl + r);
#pragma unroll
      for (int n = 0; n < 4; n++)
#pragma unroll
        for (int r = 0; r < 4; r++) oacc[n][r] *= alr[r];
    }
    // ---- P pack to bf16 pairs, kept in registers ----
    unsigned int pkw[8][2];
#pragma unroll
    for (int n = 0; n < 8; n++) {
      pkw[n][0] = cvt_pk_bf16(sacc[n][0], sacc[n][1]);
      pkw[n][1] = cvt_pk_bf16(sacc[n][2], sacc[n][3]);
    }
    // ---- PV: A-frag built via cross-quad shfl (no LDS P) ----
#pragma unroll
    for (int c = 0; c < 4; c++) {
      unsigned int a0 = __shfl(pkw[2 * c][0], qA);
      unsigned int a1 = __shfl(pkw[2 * c][1], qA);
      unsigned int a2 = __shfl(pkw[2 * c][0], qB);
      unsigned int a3 = __shfl(pkw[2 * c][1], qB);
      unsigned int b0 = __shfl(pkw[2 * c + 1][0], qA);
      unsigned int b1 = __shfl(pkw[2 * c + 1][1], qA);
      unsigned int b2 = __shfl(pkw[2 * c + 1][0], qB);
      unsigned int b3 = __shfl(pkw[2 * c + 1][1], qB);
      union { unsigned int u[4]; bf16x8 v8; } pf;
      pf.u[0] = hiN ? b0 : a0;
      pf.u[1] = hiN ? b1 : a1;
      pf.u[2] = hiN ? b2 : a2;
      pf.u[3] = hiN ? b3 : a3;
      __builtin_amdgcn_s_setprio(1);
#pragma unroll
      for (int n = 0; n < 4; n++) {
        bf16x8 vf = *(const bf16x8*)(Vc + (n * 16 + l15) * 136 + c * 32 + quad * 8);
        oacc[n] = __builtin_amdgcn_mfma_f32_16x16x32_bf16(pf.v8, vf, oacc[n], 0, 0, 0);
      }
      __builtin_amdgcn_s_setprio(0);
    }
    if (kt < qt) {  // stage prefetched tile into the other buffer (no race: buf^1)
      *(bf16x8*)(Kt[cur ^ 1] + krow * 72 + kq) = kv[0];
      *(bf16x8*)(Kt[cur ^ 1] + krow * 72 + kq + 8) = kv[1];
      *(bf16x8*)(Vt[cur ^ 1] + dr * 136 + kc8 * 16) = vv[0];
      *(bf16x8*)(Vt[cur ^ 1] + dr * 136 + kc8 * 16 + 8) = vv[1];
    }
    __syncthreads();  // single barrier: buf[cur] readers done + buf^1 staged
    cur ^= 1;
  }
  float lr[4];
#pragma unroll
  for (int r = 0; r < 4; r++) lr[r] = __shfl(l_i, srcl + r);
  for (int n = 0; n < 4; n++)
    for (int r = 0; r < 4; r++) {
      int row = q0 + 16 * w + quad * 4 + r;
      out[(size_t)(b * SS + row) * EE + h * DD + n * 16 + l15] = f2b(oacc[n][r] / lr[r]);
    }
}

extern "C" void kernel_launch(void* const* d_in, const int* in_sizes, int n_in,
                              void* d_out, int out_size, void* d_ws, size_t ws_size,
                              hipStream_t stream) {
  const float* x       = (const float*)d_in[0];
  const float* ln_w    = (const float*)d_in[1];
  const float* ln_b    = (const float*)d_in[2];
  const float* qkv_w   = (const float*)d_in[3];
  const float* qkv_b   = (const float*)d_in[4];
  const float* qk_s    = (const float*)d_in[5];
  const float* out_w   = (const float*)d_in[6];
  const float* out_b   = (const float*)d_in[7];
  const float* inv_frq = (const float*)d_in[8];

  // ws (33.55 MB): xn bf16 [8.39 MB] | qkv bf16 [25.17 MB]
  u16* ws   = (u16*)d_ws;
  u16* xn   = ws;                               // 4096*1024 (LN out, later attn out)
  u16* qkv  = ws + (size_t)4096 * 1024;         // 4096*3072 (q,k in place; V unused)
  // d_out is fp32 [16.78 MB]; stage bf16 scratch inside it while it's dead:
  u16* wq_b = (u16*)d_out;                      // [0, 6.29 MB): bf16 qkv_w
  float2* cs_tab = (float2*)((char*)d_out + 6291456);  // [6.29, 6.30 MB): cos/sin table
  u16* vt   = (u16*)d_out + (size_t)4194304;    // [8.39, 16.78 MB): bf16 V^T

  k_prep<<<7172, 256, 0, stream>>>(qkv_w, wq_b, inv_frq, cs_tab, x, ln_w, ln_b, xn);
  k_gemm_b<<<dim3(24, 32), 256, 0, stream>>>(xn, wq_b, qkv_b, qkv, vt, 4096, 3072, 1024);
  k_rotv<<<4096, 256, 0, stream>>>(qkv, cs_tab, qk_s);
  k_attn<<<dim3(32, 16), 512, 0, stream>>>(qkv, vt, xn);
  k_gemm_fw<<<dim3(8, 64), 256, 0, stream>>>(xn, out_w, out_b, (float*)d_out, 4096, 1024, 1024);
}

// Round 14
// 229.083 us; speedup vs baseline: 1.0198x; 1.0198x over previous
//
#include <hip/hip_runtime.h>

typedef unsigned short u16;
typedef __attribute__((ext_vector_type(8))) short bf16x8;   // 8 bf16 in 4 VGPRs (MFMA A/B frag)
typedef __attribute__((ext_vector_type(4))) float f32x4;    // MFMA C/D frag

#define SS 2048
#define EE 1024
#define HH 16
#define DD 64

__device__ __forceinline__ float b2f(u16 u) {
  union { unsigned int i; float f; } v; v.i = ((unsigned int)u) << 16; return v.f;
}
__device__ __forceinline__ u16 f2b(float f) {
  union { float f; unsigned int i; } v; v.f = f;
  unsigned int i = v.i;
  return (u16)((i + 0x7FFFu + ((i >> 16) & 1u)) >> 16);  // RNE
}
__device__ __forceinline__ unsigned int cvt_pk_bf16(float lo, float hi) {
  unsigned int r;
  asm("v_cvt_pk_bf16_f32 %0, %1, %2" : "=v"(r) : "v"(lo), "v"(hi));  // RNE pack, low=lo
  return r;
}

// async global->LDS, 16B per lane (m97 pattern; LDS dest = wave-uniform base + lane*16)
#define GLD16(g, l)                                                         \
  __builtin_amdgcn_global_load_lds(                                         \
      (const __attribute__((address_space(1))) unsigned int*)(g),           \
      (__attribute__((address_space(3))) unsigned int*)(l), 16, 0, 0)

// ---------------- fused prep: qkv_w cvt | trig table | LayerNorm ----------------
// blocks [0,3072): cvt qkv_w -> bf16; [3072,3076): cos/sin table; [3076,7172): LN rows
__global__ __launch_bounds__(256) void k_prep(const float* __restrict__ qkv_w,
                                              u16* __restrict__ wq_b,
                                              const float* __restrict__ inv_freq,
                                              float2* __restrict__ cs,
                                              const float* __restrict__ x,
                                              const float* __restrict__ lw,
                                              const float* __restrict__ lb,
                                              u16* __restrict__ xn) {
  const int bx = blockIdx.x, t = threadIdx.x;
  if (bx < 3072) {
    const int i = bx * 256 + t;
    float4 v = ((const float4*)qkv_w)[i];
    ushort4 o;
    o.x = f2b(v.x); o.y = f2b(v.y); o.z = f2b(v.z); o.w = f2b(v.w);
    ((ushort4*)wq_b)[i] = o;
    return;
  }
  if (bx < 3076) {
    const int i = (bx - 3072) * 256 + t;
    float th = 2048.0f * inv_freq[i];
    cs[i] = make_float2(cosf(th), sinf(th));
    return;
  }
  const int row = bx - 3076;
  float4 v = ((const float4*)(x + (size_t)row * EE))[t];
  float f0 = v.x, f1 = v.y, f2 = v.z, f3 = v.w;
  float s = f0 + f1 + f2 + f3;
  float ss = f0 * f0 + f1 * f1 + f2 * f2 + f3 * f3;
  for (int o = 1; o < 64; o <<= 1) { s += __shfl_xor(s, o); ss += __shfl_xor(ss, o); }
  __shared__ float red[8];
  int w = t >> 6;
  if ((t & 63) == 0) { red[w] = s; red[4 + w] = ss; }
  __syncthreads();
  s = red[0] + red[1] + red[2] + red[3];
  ss = red[4] + red[5] + red[6] + red[7];
  float mu = s * (1.0f / 1024.0f);
  float var = ss * (1.0f / 1024.0f) - mu * mu;
  float rstd = rsqrtf(var + 1e-5f);
  float4 wv = ((const float4*)lw)[t];
  float4 bv = ((const float4*)lb)[t];
  ushort4 o;
  o.x = f2b((f0 - mu) * rstd * wv.x + bv.x);
  o.y = f2b((f1 - mu) * rstd * wv.y + bv.y);
  o.z = f2b((f2 - mu) * rstd * wv.z + bv.z);
  o.w = f2b((f3 - mu) * rstd * wv.w + bv.w);
  ((ushort4*)(xn + (size_t)row * EE))[t] = o;
}

// ---- MFMA GEMM  C[M,N] = A[M,K] * W[N,K]^T + bias (bf16 A and W) ----
// Round-14: DOUBLE-BUFFERED LDS with prefetch-before-compute — GLD16 for tile
// k+1 issued BEFORE the MFMA phase, so the barrier's vmcnt-drain lands after
// ~400 cyc of compute (HBM latency partially hidden); ONE barrier/iter (was 2).
// V-direct epilogue: V col-blocks (n0>=2048) stage through a 64-col padded LDS
// transpose buffer in two passes, then write V^T with contiguous 64B segments.
__global__ __launch_bounds__(256) void k_gemm_b(const u16* __restrict__ A,
                                                const u16* __restrict__ W,
                                                const float* __restrict__ bias,
                                                u16* __restrict__ C,
                                                u16* __restrict__ VT,
                                                int M, int N, int K) {
  __shared__ __align__(16) u16 As[2][128 * 32];   // 32 KB
  __shared__ __align__(16) u16 Ws[2][128 * 32];
  __shared__ __align__(16) u16 Tt[64 * 136];      // 17.4 KB V^T staging (2 passes)
  const int t = threadIdx.x;
  const int m0 = blockIdx.y * 128, n0 = blockIdx.x * 128;
  const int lane = t & 63, w = t >> 6, quad = lane >> 4, l15 = lane & 15;
  const int wm = (w & 1) * 64, wn = (w >> 1) * 64;

  f32x4 zero4 = {0.f, 0.f, 0.f, 0.f};
  f32x4 acc[4][4];
  for (int mi = 0; mi < 4; mi++)
    for (int ni = 0; ni < 4; ni++) acc[mi][ni] = zero4;

  const u16* Ag = A + (size_t)(m0 + (t >> 2)) * K + (t & 3) * 8;
  const u16* Wg = W + (size_t)(n0 + (t >> 2)) * K + (t & 3) * 8;
  const size_t rowskip = (size_t)64 * K;

  // prologue: stage k=0 into buf 0
  GLD16(Ag, As[0] + t * 8);
  GLD16(Ag + rowskip, As[0] + 2048 + t * 8);
  GLD16(Wg, Ws[0] + t * 8);
  GLD16(Wg + rowskip, Ws[0] + 2048 + t * 8);
  __syncthreads();
  int cur = 0;

  for (int k0 = 0; k0 < K; k0 += 32) {
    if (k0 + 32 < K) {  // prefetch next K-tile into buf^1 (disjoint; no race)
      GLD16(Ag + k0 + 32, As[cur ^ 1] + t * 8);
      GLD16(Ag + rowskip + k0 + 32, As[cur ^ 1] + 2048 + t * 8);
      GLD16(Wg + k0 + 32, Ws[cur ^ 1] + t * 8);
      GLD16(Wg + rowskip + k0 + 32, Ws[cur ^ 1] + 2048 + t * 8);
    }
    bf16x8 af[4], wf[4];
#pragma unroll
    for (int i = 0; i < 4; i++) {
      af[i] = *(const bf16x8*)(As[cur] + (wm + i * 16 + l15) * 32 + quad * 8);
      wf[i] = *(const bf16x8*)(Ws[cur] + (wn + i * 16 + l15) * 32 + quad * 8);
    }
#pragma unroll
    for (int mi = 0; mi < 4; mi++)
#pragma unroll
      for (int ni = 0; ni < 4; ni++)
        acc[mi][ni] = __builtin_amdgcn_mfma_f32_16x16x32_bf16(af[mi], wf[ni], acc[mi][ni], 0, 0, 0);
    __syncthreads();  // drains prefetch loads + all reads of buf[cur] done
    cur ^= 1;
  }

  if (n0 < 2048) {  // Q/K sections: row-major write to qkv (block-uniform branch)
    for (int mi = 0; mi < 4; mi++)
      for (int ni = 0; ni < 4; ni++) {
        int col = n0 + wn + ni * 16 + l15;
        float bb = bias[col];
        for (int r = 0; r < 4; r++) {
          int grow = m0 + wm + mi * 16 + quad * 4 + r;
          C[(size_t)grow * N + col] = f2b(acc[mi][ni][r] + bb);
        }
      }
  } else {  // V section: two-pass LDS transpose, then coalesced V^T write
#pragma unroll
    for (int p = 0; p < 2; p++) {
      if (wn == p * 64) {  // warps owning this 64-col half write their frags
        for (int mi = 0; mi < 4; mi++)
          for (int ni = 0; ni < 4; ni++) {
            int cl = ni * 16 + l15;               // local col 0..63
            int sIn = wm + mi * 16 + quad * 4;    // local row (4 consecutive s)
            float bb = bias[n0 + p * 64 + cl];
            ushort4 o;
            o.x = f2b(acc[mi][ni][0] + bb);
            o.y = f2b(acc[mi][ni][1] + bb);
            o.z = f2b(acc[mi][ni][2] + bb);
            o.w = f2b(acc[mi][ni][3] + bb);
            *(ushort4*)(Tt + cl * 136 + sIn) = o;
          }
      }
      __syncthreads();
      {  // dump: thread t owns col t>>2, 32-u16 segment t&3 (64 B contiguous)
        int cl = t >> 2, seg = t & 3;
        int col = (n0 - 2048) + p * 64 + cl;
        int h = col >> 6, d = col & 63;
        int bb_ = m0 >> 11, s0 = (m0 & 2047) + seg * 32;
        u16* dst = VT + ((size_t)((bb_ * 16 + h) * 64 + d)) * SS + s0;
        const u16* srcT = Tt + cl * 136 + seg * 32;
#pragma unroll
        for (int it = 0; it < 4; it++)
          *(bf16x8*)(dst + it * 8) = *(const bf16x8*)(srcT + it * 8);
      }
      if (p == 0) __syncthreads();  // Tt reads done before pass-B overwrite
    }
  }
}

// ---- MFMA GEMM with fp32 W (converted in-flight) ----
// Round-14: same dbuf+prefetch pattern — As via GLD16 dbuf; W fp32 reg-prefetch,
// cvt_pk + ds_write into Ws[buf^1] for k+1 after this iter's MFMA. 1 barrier/iter.
__global__ __launch_bounds__(256) void k_gemm_fw(const u16* __restrict__ A,
                                                 const float* __restrict__ W,
                                                 const float* __restrict__ bias,
                                                 float* __restrict__ C,
                                                 int M, int N, int K) {
  __shared__ __align__(16) u16 As[2][64 * 32];    // 16 KB
  __shared__ __align__(16) u16 Ws[2][128 * 32];   // 32 KB
  const int t = threadIdx.x;
  const int m0 = blockIdx.y * 64, n0 = blockIdx.x * 128;
  const int lane = t & 63, w = t >> 6, quad = lane >> 4, l15 = lane & 15;
  const int wm = (w & 1) * 32, wn = (w >> 1) * 64;

  f32x4 zero4 = {0.f, 0.f, 0.f, 0.f};
  f32x4 acc[2][4];
  for (int mi = 0; mi < 2; mi++)
    for (int ni = 0; ni < 4; ni++) acc[mi][ni] = zero4;

  const u16* Ag = A + (size_t)(m0 + (t >> 2)) * K + (t & 3) * 8;
  const float* Wg0 = W + (size_t)(n0 + (t >> 2)) * K + (t & 3) * 8;
  const float* Wg1 = Wg0 + (size_t)64 * K;

  // prologue: k=0 staged into buf 0
  float4 wa = *(const float4*)(Wg0);
  float4 wb = *(const float4*)(Wg0 + 4);
  float4 wc = *(const float4*)(Wg1);
  float4 wd = *(const float4*)(Wg1 + 4);
  GLD16(Ag, As[0] + t * 8);
  {
    union { unsigned int u[4]; bf16x8 v8; } p0, p1;
    p0.u[0] = cvt_pk_bf16(wa.x, wa.y); p0.u[1] = cvt_pk_bf16(wa.z, wa.w);
    p0.u[2] = cvt_pk_bf16(wb.x, wb.y); p0.u[3] = cvt_pk_bf16(wb.z, wb.w);
    p1.u[0] = cvt_pk_bf16(wc.x, wc.y); p1.u[1] = cvt_pk_bf16(wc.z, wc.w);
    p1.u[2] = cvt_pk_bf16(wd.x, wd.y); p1.u[3] = cvt_pk_bf16(wd.z, wd.w);
    *(bf16x8*)(Ws[0] + t * 8) = p0.v8;
    *(bf16x8*)(Ws[0] + 2048 + t * 8) = p1.v8;
  }
  __syncthreads();
  int cur = 0;

  for (int k0 = 0; k0 < K; k0 += 32) {
    const bool pref = (k0 + 32 < K);
    if (pref) {  // issue next tile's loads early (latency hidden under MFMA)
      GLD16(Ag + k0 + 32, As[cur ^ 1] + t * 8);
      wa = *(const float4*)(Wg0 + k0 + 32);
      wb = *(const float4*)(Wg0 + k0 + 36);
      wc = *(const float4*)(Wg1 + k0 + 32);
      wd = *(const float4*)(Wg1 + k0 + 36);
    }
    bf16x8 af[2], wf[4];
#pragma unroll
    for (int i = 0; i < 2; i++)
      af[i] = *(const bf16x8*)(As[cur] + (wm + i * 16 + l15) * 32 + quad * 8);
#pragma unroll
    for (int i = 0; i < 4; i++)
      wf[i] = *(const bf16x8*)(Ws[cur] + (wn + i * 16 + l15) * 32 + quad * 8);
#pragma unroll
    for (int mi = 0; mi < 2; mi++)
#pragma unroll
      for (int ni = 0; ni < 4; ni++)
        acc[mi][ni] = __builtin_amdgcn_mfma_f32_16x16x32_bf16(af[mi], wf[ni], acc[mi][ni], 0, 0, 0);
    if (pref) {  // convert + stage W(k+1) into buf^1 (disjoint from buf[cur] readers)
      union { unsigned int u[4]; bf16x8 v8; } p0, p1;
      p0.u[0] = cvt_pk_bf16(wa.x, wa.y); p0.u[1] = cvt_pk_bf16(wa.z, wa.w);
      p0.u[2] = cvt_pk_bf16(wb.x, wb.y); p0.u[3] = cvt_pk_bf16(wb.z, wb.w);
      p1.u[0] = cvt_pk_bf16(wc.x, wc.y); p1.u[1] = cvt_pk_bf16(wc.z, wc.w);
      p1.u[2] = cvt_pk_bf16(wd.x, wd.y); p1.u[3] = cvt_pk_bf16(wd.z, wd.w);
      *(bf16x8*)(Ws[cur ^ 1] + t * 8) = p0.v8;
      *(bf16x8*)(Ws[cur ^ 1] + 2048 + t * 8) = p1.v8;
    }
    __syncthreads();
    cur ^= 1;
  }
  for (int mi = 0; mi < 2; mi++)
    for (int ni = 0; ni < 4; ni++) {
      int col = n0 + wn + ni * 16 + l15;
      float bb = bias[col];
      for (int r = 0; r < 4; r++) {
        int grow = m0 + wm + mi * 16 + quad * 4 + r;
        C[(size_t)grow * N + col] = acc[mi][ni][r] + bb;
      }
    }
}

// ------ rotate (table) + per-head l2norm + qknorm scale (vtrans fused into gemm) ------
__global__ __launch_bounds__(256) void k_rotv(u16* __restrict__ qkv,
                                              const float2* __restrict__ cs_tab,
                                              const float* __restrict__ scale_p) {
  __shared__ float qf[1024];
  __shared__ float kf[1024];
  const int row = blockIdx.x, t = threadIdx.x;
  u16* qr = qkv + (size_t)row * 3072;
  u16* kr = qr + 1024;
  ushort4 qv = ((const ushort4*)qr)[t];
  ushort4 kv = ((const ushort4*)kr)[t];
  *(float4*)(qf + 4 * t) = make_float4(b2f(qv.x), b2f(qv.y), b2f(qv.z), b2f(qv.w));
  *(float4*)(kf + 4 * t) = make_float4(b2f(kv.x), b2f(kv.y), b2f(kv.z), b2f(kv.w));
  __syncthreads();
  const float scale = scale_p[0];
  float rq[4], rk[4];
#pragma unroll
  for (int u = 0; u < 4; u++) {
    int j = 4 * t + u;
    float2 cs = cs_tab[j];
    float qrot = (j < 512) ? -qf[2 * j + 1] : qf[2 * (j - 512)];
    float krot = (j < 512) ? -kf[2 * j + 1] : kf[2 * (j - 512)];
    rq[u] = qf[j] * cs.x + qrot * cs.y;
    rk[u] = kf[j] * cs.x + krot * cs.y;
  }
  float ssq = rq[0] * rq[0] + rq[1] * rq[1] + rq[2] * rq[2] + rq[3] * rq[3];
  float ssk = rk[0] * rk[0] + rk[1] * rk[1] + rk[2] * rk[2] + rk[3] * rk[3];
  for (int o = 1; o < 16; o <<= 1) { ssq += __shfl_xor(ssq, o); ssk += __shfl_xor(ssk, o); }
  float qs = scale / fmaxf(sqrtf(ssq), 1e-12f);
  float ks = scale / fmaxf(sqrtf(ssk), 1e-12f);
  ushort4 qo, ko;
  qo.x = f2b(rq[0] * qs); qo.y = f2b(rq[1] * qs); qo.z = f2b(rq[2] * qs); qo.w = f2b(rq[3] * qs);
  ko.x = f2b(rk[0] * ks); ko.y = f2b(rk[1] * ks); ko.z = f2b(rk[2] * ks); ko.w = f2b(rk[3] * ks);
  ((ushort4*)qr)[t] = qo;
  ((ushort4*)kr)[t] = ko;
}

// ---------------- causal flash attention (round-11 proven version) ----------------
// QBLK=128 via 8 warps; KBLK=128. Grid (32,16): bh = blockIdx.x, qt = y<8 ? y : 23-y
// (co-resident block pairs f,f+256 share bh -> K/V L2-resident; qt sums to 15).
// SWAPPED QK^T -> lane-local softmax (+2 shfl_xor); in-register P via cross-quad shfl.
// (T13/T5 removed: implicated in the round-12 regression; m190 lockstep precedent.)
__global__ __launch_bounds__(512, 4) void k_attn(const u16* __restrict__ qkv,
                                                 const u16* __restrict__ vt,
                                                 u16* __restrict__ out) {
  __shared__ __align__(16) u16 Kt[2][128 * 72];    // K rows (d=0..63 + pad)
  __shared__ __align__(16) u16 Vt[2][64 * 136];    // V^T rows d, k=0..127 + pad
  const int bh = blockIdx.x;
  const int y = blockIdx.y;
  const int qt = (y < 8) ? y : 23 - y;             // 128-row q-tile, 0..15
  const int b = bh >> 4, h = bh & 15;
  const int t = threadIdx.x, w = t >> 6, lane = t & 63, quad = lane >> 4, l15 = lane & 15;
  const int krow = t >> 2, kq = (t & 3) * 16;  // K staging: row 0..127, 16-u16 quarter
  const int dr = t >> 3, kc8 = t & 7;          // V staging: d-row 0..63, 16-k eighth
  const int srcl = (lane & 48) + ((lane >> 4) << 2);  // 20*quad: state-holder base lane
  const int qA = ((lane >> 4) & 1) * 32 + l15;        // P-exchange src lane
  const int qB = qA + 16;
  const bool hiN = (quad >> 1) & 1;
  const u16* kn = qkv + 1024;
  f32x4 zero4 = {0.f, 0.f, 0.f, 0.f};
  const int q0 = qt * 128;

  bf16x8 qf[2];
  {
    const u16* qrow = qkv + (size_t)(b * SS + q0 + 16 * w + l15) * 3072 + h * DD;
    qf[0] = *(const bf16x8*)(qrow + quad * 8);
    qf[1] = *(const bf16x8*)(qrow + 32 + quad * 8);
  }
  f32x4 oacc[4];
  for (int n = 0; n < 4; n++) oacc[n] = zero4;
  float m_i = -1e30f, l_i = 0.f;   // per-lane: state for q-row 16w+l15

  bf16x8 kv[2], vv[2];
  // prologue: load & stage tile kt=0 into buf 0
  {
    const u16* krg = kn + (size_t)(b * SS + krow) * 3072 + h * DD + kq;
    kv[0] = *(const bf16x8*)(krg);
    kv[1] = *(const bf16x8*)(krg + 8);
    const u16* vrg = vt + (size_t)(bh * DD + dr) * SS + kc8 * 16;
    vv[0] = *(const bf16x8*)(vrg);
    vv[1] = *(const bf16x8*)(vrg + 8);
  }
  *(bf16x8*)(Kt[0] + krow * 72 + kq) = kv[0];
  *(bf16x8*)(Kt[0] + krow * 72 + kq + 8) = kv[1];
  *(bf16x8*)(Vt[0] + dr * 136 + kc8 * 16) = vv[0];
  *(bf16x8*)(Vt[0] + dr * 136 + kc8 * 16 + 8) = vv[1];
  __syncthreads();
  int cur = 0;

  for (int kt = 0; kt <= qt; kt++) {
    if (kt < qt) {  // prefetch next tile into regs; staged into buf^1 below
      const int k0n = (kt + 1) * 128;
      const u16* krg = kn + (size_t)(b * SS + k0n + krow) * 3072 + h * DD + kq;
      kv[0] = *(const bf16x8*)(krg);
      kv[1] = *(const bf16x8*)(krg + 8);
      const u16* vrg = vt + (size_t)(bh * DD + dr) * SS + k0n + kc8 * 16;
      vv[0] = *(const bf16x8*)(vrg);
      vv[1] = *(const bf16x8*)(vrg + 8);
    }
    const u16* Kc = Kt[cur];
    const u16* Vc = Vt[cur];
    // ---- swapped QK^T: A = K-group (16 k-rows), B = Q ----
    f32x4 sacc[8];
#pragma unroll
    for (int n = 0; n < 8; n++) {
      sacc[n] = zero4;
#pragma unroll
      for (int c = 0; c < 2; c++) {
        bf16x8 kfrag = *(const bf16x8*)(Kc + (n * 16 + l15) * 72 + c * 32 + quad * 8);
        sacc[n] = __builtin_amdgcn_mfma_f32_16x16x32_bf16(kfrag, qf[c], sacc[n], 0, 0, 0);
      }
    }
    if (kt == qt) {  // diagonal: mask k > q-row-in-tile; k = 16n+4quad+r, q = 16w+l15
      const int qrow = 16 * w + l15, kbase = 4 * quad;
#pragma unroll
      for (int n = 0; n < 8; n++)
#pragma unroll
        for (int r = 0; r < 4; r++)
          if (16 * n + kbase + r > qrow) sacc[n][r] = -1e30f;
    }
    // ---- lane-local softmax for q-row 16w+l15 ----
    float mx = -1e30f;
#pragma unroll
    for (int n = 0; n < 8; n++)
#pragma unroll
      for (int r = 0; r < 4; r++) mx = fmaxf(mx, sacc[n][r]);
    mx = fmaxf(mx, __shfl_xor(mx, 16));
    mx = fmaxf(mx, __shfl_xor(mx, 32));
    float mn = fmaxf(m_i, mx);
    float al = __expf(m_i - mn);
    m_i = mn;
    float rs = 0.f;
#pragma unroll
    for (int n = 0; n < 8; n++)
#pragma unroll
      for (int r = 0; r < 4; r++) {
        float p = __expf(sacc[n][r] - mn);
        sacc[n][r] = p;
        rs += p;
      }
    rs += __shfl_xor(rs, 16);
    rs += __shfl_xor(rs, 32);
    l_i = al * l_i + rs;
    // broadcast al to O-row holders (O row q = quad*4+r; state at lane 20*quad+r)
    float alr[4];
#pragma unroll
    for (int r = 0; r < 4; r++) alr[r] = __shfl(al, srcl + r);
#pragma unroll
    for (int n = 0; n < 4; n++)
#pragma unroll
      for (int r = 0; r < 4; r++) oacc[n][r] *= alr[r];
    // ---- P pack to bf16 pairs, kept in registers ----
    unsigned int pkw[8][2];
#pragma unroll
    for (int n = 0; n < 8; n++) {
      pkw[n][0] = cvt_pk_bf16(sacc[n][0], sacc[n][1]);
      pkw[n][1] = cvt_pk_bf16(sacc[n][2], sacc[n][3]);
    }
    // ---- PV: A-frag built via cross-quad shfl (no LDS P) ----
#pragma unroll
    for (int c = 0; c < 4; c++) {
      unsigned int a0 = __shfl(pkw[2 * c][0], qA);
      unsigned int a1 = __shfl(pkw[2 * c][1], qA);
      unsigned int a2 = __shfl(pkw[2 * c][0], qB);
      unsigned int a3 = __shfl(pkw[2 * c][1], qB);
      unsigned int b0 = __shfl(pkw[2 * c + 1][0], qA);
      unsigned int b1 = __shfl(pkw[2 * c + 1][1], qA);
      unsigned int b2 = __shfl(pkw[2 * c + 1][0], qB);
      unsigned int b3 = __shfl(pkw[2 * c + 1][1], qB);
      union { unsigned int u[4]; bf16x8 v8; } pf;
      pf.u[0] = hiN ? b0 : a0;
      pf.u[1] = hiN ? b1 : a1;
      pf.u[2] = hiN ? b2 : a2;
      pf.u[3] = hiN ? b3 : a3;
#pragma unroll
      for (int n = 0; n < 4; n++) {
        bf16x8 vf = *(const bf16x8*)(Vc + (n * 16 + l15) * 136 + c * 32 + quad * 8);
        oacc[n] = __builtin_amdgcn_mfma_f32_16x16x32_bf16(pf.v8, vf, oacc[n], 0, 0, 0);
      }
    }
    if (kt < qt) {  // stage prefetched tile into the other buffer (no race: buf^1)
      *(bf16x8*)(Kt[cur ^ 1] + krow * 72 + kq) = kv[0];
      *(bf16x8*)(Kt[cur ^ 1] + krow * 72 + kq + 8) = kv[1];
      *(bf16x8*)(Vt[cur ^ 1] + dr * 136 + kc8 * 16) = vv[0];
      *(bf16x8*)(Vt[cur ^ 1] + dr * 136 + kc8 * 16 + 8) = vv[1];
    }
    __syncthreads();  // single barrier: buf[cur] readers done + buf^1 staged
    cur ^= 1;
  }
  float lr[4];
#pragma unroll
  for (int r = 0; r < 4; r++) lr[r] = __shfl(l_i, srcl + r);
  for (int n = 0; n < 4; n++)
    for (int r = 0; r < 4; r++) {
      int row = q0 + 16 * w + quad * 4 + r;
      out[(size_t)(b * SS + row) * EE + h * DD + n * 16 + l15] = f2b(oacc[n][r] / lr[r]);
    }
}

extern "C" void kernel_launch(void* const* d_in, const int* in_sizes, int n_in,
                              void* d_out, int out_size, void* d_ws, size_t ws_size,
                              hipStream_t stream) {
  const float* x       = (const float*)d_in[0];
  const float* ln_w    = (const float*)d_in[1];
  const float* ln_b    = (const float*)d_in[2];
  const float* qkv_w   = (const float*)d_in[3];
  const float* qkv_b   = (const float*)d_in[4];
  const float* qk_s    = (const float*)d_in[5];
  const float* out_w   = (const float*)d_in[6];
  const float* out_b   = (const float*)d_in[7];
  const float* inv_frq = (const float*)d_in[8];

  // ws (33.55 MB): xn bf16 [8.39 MB] | qkv bf16 [25.17 MB]
  u16* ws   = (u16*)d_ws;
  u16* xn   = ws;                               // 4096*1024 (LN out, later attn out)
  u16* qkv  = ws + (size_t)4096 * 1024;         // 4096*3072 (q,k in place; V unused)
  // d_out is fp32 [16.78 MB]; stage bf16 scratch inside it while it's dead:
  u16* wq_b = (u16*)d_out;                      // [0, 6.29 MB): bf16 qkv_w
  float2* cs_tab = (float2*)((char*)d_out + 6291456);  // [6.29, 6.30 MB): cos/sin table
  u16* vt   = (u16*)d_out + (size_t)4194304;    // [8.39, 16.78 MB): bf16 V^T

  k_prep<<<7172, 256, 0, stream>>>(qkv_w, wq_b, inv_frq, cs_tab, x, ln_w, ln_b, xn);
  k_gemm_b<<<dim3(24, 32), 256, 0, stream>>>(xn, wq_b, qkv_b, qkv, vt, 4096, 3072, 1024);
  k_rotv<<<4096, 256, 0, stream>>>(qkv, cs_tab, qk_s);
  k_attn<<<dim3(32, 16), 512, 0, stream>>>(qkv, vt, xn);
  k_gemm_fw<<<dim3(8, 64), 256, 0, stream>>>(xn, out_w, out_b, (float*)d_out, 4096, 1024, 1024);
}

// Round 16
// 212.656 us; speedup vs baseline: 1.0986x; 1.0772x over previous
//
#include <hip/hip_runtime.h>

typedef unsigned short u16;
typedef __attribute__((ext_vector_type(8))) short bf16x8;   // 8 bf16 in 4 VGPRs (MFMA A/B frag)
typedef __attribute__((ext_vector_type(4))) float f32x4;    // MFMA C/D frag

#define SS 2048
#define EE 1024
#define HH 16
#define DD 64

__device__ __forceinline__ float b2f(u16 u) {
  union { unsigned int i; float f; } v; v.i = ((unsigned int)u) << 16; return v.f;
}
__device__ __forceinline__ u16 f2b(float f) {
  union { float f; unsigned int i; } v; v.f = f;
  unsigned int i = v.i;
  return (u16)((i + 0x7FFFu + ((i >> 16) & 1u)) >> 16);  // RNE
}
__device__ __forceinline__ unsigned int cvt_pk_bf16(float lo, float hi) {
  unsigned int r;
  asm("v_cvt_pk_bf16_f32 %0, %1, %2" : "=v"(r) : "v"(lo), "v"(hi));  // RNE pack, low=lo
  return r;
}

// async global->LDS, 16B per lane (m97 pattern; LDS dest = wave-uniform base + lane*16)
#define GLD16(g, l)                                                         \
  __builtin_amdgcn_global_load_lds(                                         \
      (const __attribute__((address_space(1))) unsigned int*)(g),           \
      (__attribute__((address_space(3))) unsigned int*)(l), 16, 0, 0)

// ---------------- fused prep: qkv_w cvt | trig table | LayerNorm ----------------
// blocks [0,3072): cvt qkv_w -> bf16; [3072,3076): cos/sin table; [3076,7172): LN rows
__global__ __launch_bounds__(256) void k_prep(const float* __restrict__ qkv_w,
                                              u16* __restrict__ wq_b,
                                              const float* __restrict__ inv_freq,
                                              float2* __restrict__ cs,
                                              const float* __restrict__ x,
                                              const float* __restrict__ lw,
                                              const float* __restrict__ lb,
                                              u16* __restrict__ xn) {
  const int bx = blockIdx.x, t = threadIdx.x;
  if (bx < 3072) {
    const int i = bx * 256 + t;
    float4 v = ((const float4*)qkv_w)[i];
    ushort4 o;
    o.x = f2b(v.x); o.y = f2b(v.y); o.z = f2b(v.z); o.w = f2b(v.w);
    ((ushort4*)wq_b)[i] = o;
    return;
  }
  if (bx < 3076) {
    const int i = (bx - 3072) * 256 + t;
    float th = 2048.0f * inv_freq[i];
    cs[i] = make_float2(cosf(th), sinf(th));
    return;
  }
  const int row = bx - 3076;
  float4 v = ((const float4*)(x + (size_t)row * EE))[t];
  float f0 = v.x, f1 = v.y, f2 = v.z, f3 = v.w;
  float s = f0 + f1 + f2 + f3;
  float ss = f0 * f0 + f1 * f1 + f2 * f2 + f3 * f3;
  for (int o = 1; o < 64; o <<= 1) { s += __shfl_xor(s, o); ss += __shfl_xor(ss, o); }
  __shared__ float red[8];
  int w = t >> 6;
  if ((t & 63) == 0) { red[w] = s; red[4 + w] = ss; }
  __syncthreads();
  s = red[0] + red[1] + red[2] + red[3];
  ss = red[4] + red[5] + red[6] + red[7];
  float mu = s * (1.0f / 1024.0f);
  float var = ss * (1.0f / 1024.0f) - mu * mu;
  float rstd = rsqrtf(var + 1e-5f);
  float4 wv = ((const float4*)lw)[t];
  float4 bv = ((const float4*)lb)[t];
  ushort4 o;
  o.x = f2b((f0 - mu) * rstd * wv.x + bv.x);
  o.y = f2b((f1 - mu) * rstd * wv.y + bv.y);
  o.z = f2b((f2 - mu) * rstd * wv.z + bv.z);
  o.w = f2b((f3 - mu) * rstd * wv.w + bv.w);
  ((ushort4*)(xn + (size_t)row * EE))[t] = o;
}

// ---- MFMA GEMM  C[M,N] = A[M,K] * W[N,K]^T + bias (bf16 A and W) ----
// Plain row-major epilogue + dbuf/prefetch-before-compute (1 barrier/iter).
__global__ __launch_bounds__(256) void k_gemm_b(const u16* __restrict__ A,
                                                const u16* __restrict__ W,
                                                const float* __restrict__ bias,
                                                u16* __restrict__ C,
                                                int M, int N, int K) {
  __shared__ __align__(16) u16 As[2][128 * 32];   // 16 KB
  __shared__ __align__(16) u16 Ws[2][128 * 32];   // 16 KB
  const int t = threadIdx.x;
  const int m0 = blockIdx.y * 128, n0 = blockIdx.x * 128;
  const int lane = t & 63, w = t >> 6, quad = lane >> 4, l15 = lane & 15;
  const int wm = (w & 1) * 64, wn = (w >> 1) * 64;

  f32x4 zero4 = {0.f, 0.f, 0.f, 0.f};
  f32x4 acc[4][4];
  for (int mi = 0; mi < 4; mi++)
    for (int ni = 0; ni < 4; ni++) acc[mi][ni] = zero4;

  const u16* Ag = A + (size_t)(m0 + (t >> 2)) * K + (t & 3) * 8;
  const u16* Wg = W + (size_t)(n0 + (t >> 2)) * K + (t & 3) * 8;
  const size_t rowskip = (size_t)64 * K;

  // prologue: stage k=0 into buf 0
  GLD16(Ag, As[0] + t * 8);
  GLD16(Ag + rowskip, As[0] + 2048 + t * 8);
  GLD16(Wg, Ws[0] + t * 8);
  GLD16(Wg + rowskip, Ws[0] + 2048 + t * 8);
  __syncthreads();
  int cur = 0;

  for (int k0 = 0; k0 < K; k0 += 32) {
    if (k0 + 32 < K) {  // prefetch next K-tile into buf^1 (disjoint; no race)
      GLD16(Ag + k0 + 32, As[cur ^ 1] + t * 8);
      GLD16(Ag + rowskip + k0 + 32, As[cur ^ 1] + 2048 + t * 8);
      GLD16(Wg + k0 + 32, Ws[cur ^ 1] + t * 8);
      GLD16(Wg + rowskip + k0 + 32, Ws[cur ^ 1] + 2048 + t * 8);
    }
    bf16x8 af[4], wf[4];
#pragma unroll
    for (int i = 0; i < 4; i++) {
      af[i] = *(const bf16x8*)(As[cur] + (wm + i * 16 + l15) * 32 + quad * 8);
      wf[i] = *(const bf16x8*)(Ws[cur] + (wn + i * 16 + l15) * 32 + quad * 8);
    }
#pragma unroll
    for (int mi = 0; mi < 4; mi++)
#pragma unroll
      for (int ni = 0; ni < 4; ni++)
        acc[mi][ni] = __builtin_amdgcn_mfma_f32_16x16x32_bf16(af[mi], wf[ni], acc[mi][ni], 0, 0, 0);
    __syncthreads();  // drains prefetch loads + all reads of buf[cur] done
    cur ^= 1;
  }
  for (int mi = 0; mi < 4; mi++)
    for (int ni = 0; ni < 4; ni++) {
      int col = n0 + wn + ni * 16 + l15;
      float bb = bias[col];
      for (int r = 0; r < 4; r++) {
        int grow = m0 + wm + mi * 16 + quad * 4 + r;
        C[(size_t)grow * N + col] = f2b(acc[mi][ni][r] + bb);
      }
    }
}

// ---- MFMA GEMM with fp32 W (converted in-flight) ----
// dbuf + prefetch-before-compute: As via GLD16 dbuf; W fp32 reg-prefetch,
// cvt_pk + ds_write into Ws[buf^1] after this iter's MFMA. 1 barrier/iter.
__global__ __launch_bounds__(256) void k_gemm_fw(const u16* __restrict__ A,
                                                 const float* __restrict__ W,
                                                 const float* __restrict__ bias,
                                                 float* __restrict__ C,
                                                 int M, int N, int K) {
  __shared__ __align__(16) u16 As[2][64 * 32];    // 8 KB
  __shared__ __align__(16) u16 Ws[2][128 * 32];   // 16 KB
  const int t = threadIdx.x;
  const int m0 = blockIdx.y * 64, n0 = blockIdx.x * 128;
  const int lane = t & 63, w = t >> 6, quad = lane >> 4, l15 = lane & 15;
  const int wm = (w & 1) * 32, wn = (w >> 1) * 64;

  f32x4 zero4 = {0.f, 0.f, 0.f, 0.f};
  f32x4 acc[2][4];
  for (int mi = 0; mi < 2; mi++)
    for (int ni = 0; ni < 4; ni++) acc[mi][ni] = zero4;

  const u16* Ag = A + (size_t)(m0 + (t >> 2)) * K + (t & 3) * 8;
  const float* Wg0 = W + (size_t)(n0 + (t >> 2)) * K + (t & 3) * 8;
  const float* Wg1 = Wg0 + (size_t)64 * K;

  // prologue: k=0 staged into buf 0
  float4 wa = *(const float4*)(Wg0);
  float4 wb = *(const float4*)(Wg0 + 4);
  float4 wc = *(const float4*)(Wg1);
  float4 wd = *(const float4*)(Wg1 + 4);
  GLD16(Ag, As[0] + t * 8);
  {
    union { unsigned int u[4]; bf16x8 v8; } p0, p1;
    p0.u[0] = cvt_pk_bf16(wa.x, wa.y); p0.u[1] = cvt_pk_bf16(wa.z, wa.w);
    p0.u[2] = cvt_pk_bf16(wb.x, wb.y); p0.u[3] = cvt_pk_bf16(wb.z, wb.w);
    p1.u[0] = cvt_pk_bf16(wc.x, wc.y); p1.u[1] = cvt_pk_bf16(wc.z, wc.w);
    p1.u[2] = cvt_pk_bf16(wd.x, wd.y); p1.u[3] = cvt_pk_bf16(wd.z, wd.w);
    *(bf16x8*)(Ws[0] + t * 8) = p0.v8;
    *(bf16x8*)(Ws[0] + 2048 + t * 8) = p1.v8;
  }
  __syncthreads();
  int cur = 0;

  for (int k0 = 0; k0 < K; k0 += 32) {
    const bool pref = (k0 + 32 < K);
    if (pref) {  // issue next tile's loads early (latency hidden under MFMA)
      GLD16(Ag + k0 + 32, As[cur ^ 1] + t * 8);
      wa = *(const float4*)(Wg0 + k0 + 32);
      wb = *(const float4*)(Wg0 + k0 + 36);
      wc = *(const float4*)(Wg1 + k0 + 32);
      wd = *(const float4*)(Wg1 + k0 + 36);
    }
    bf16x8 af[2], wf[4];
#pragma unroll
    for (int i = 0; i < 2; i++)
      af[i] = *(const bf16x8*)(As[cur] + (wm + i * 16 + l15) * 32 + quad * 8);
#pragma unroll
    for (int i = 0; i < 4; i++)
      wf[i] = *(const bf16x8*)(Ws[cur] + (wn + i * 16 + l15) * 32 + quad * 8);
#pragma unroll
    for (int mi = 0; mi < 2; mi++)
#pragma unroll
      for (int ni = 0; ni < 4; ni++)
        acc[mi][ni] = __builtin_amdgcn_mfma_f32_16x16x32_bf16(af[mi], wf[ni], acc[mi][ni], 0, 0, 0);
    if (pref) {  // convert + stage W(k+1) into buf^1 (disjoint from buf[cur] readers)
      union { unsigned int u[4]; bf16x8 v8; } p0, p1;
      p0.u[0] = cvt_pk_bf16(wa.x, wa.y); p0.u[1] = cvt_pk_bf16(wa.z, wa.w);
      p0.u[2] = cvt_pk_bf16(wb.x, wb.y); p0.u[3] = cvt_pk_bf16(wb.z, wb.w);
      p1.u[0] = cvt_pk_bf16(wc.x, wc.y); p1.u[1] = cvt_pk_bf16(wc.z, wc.w);
      p1.u[2] = cvt_pk_bf16(wd.x, wd.y); p1.u[3] = cvt_pk_bf16(wd.z, wd.w);
      *(bf16x8*)(Ws[cur ^ 1] + t * 8) = p0.v8;
      *(bf16x8*)(Ws[cur ^ 1] + 2048 + t * 8) = p1.v8;
    }
    __syncthreads();
    cur ^= 1;
  }
  for (int mi = 0; mi < 2; mi++)
    for (int ni = 0; ni < 4; ni++) {
      int col = n0 + wn + ni * 16 + l15;
      float bb = bias[col];
      for (int r = 0; r < 4; r++) {
        int grow = m0 + wm + mi * 16 + quad * 4 + r;
        C[(size_t)grow * N + col] = acc[mi][ni][r] + bb;
      }
    }
}

// ------ fused: rotate+l2norm+scale (all 4096 rows) | V transpose (blocks < 1024) ------
// (round-11 proven version)
__global__ __launch_bounds__(256) void k_rotv(u16* __restrict__ qkv,
                                              const float2* __restrict__ cs_tab,
                                              const float* __restrict__ scale_p,
                                              u16* __restrict__ vt) {
  __shared__ float qf[1024];
  __shared__ float kf[1024];
  __shared__ __align__(16) u16 tile[64 * 72];
  const int row = blockIdx.x, t = threadIdx.x;
  {
    u16* qr = qkv + (size_t)row * 3072;
    u16* kr = qr + 1024;
    ushort4 qv = ((const ushort4*)qr)[t];
    ushort4 kv = ((const ushort4*)kr)[t];
    *(float4*)(qf + 4 * t) = make_float4(b2f(qv.x), b2f(qv.y), b2f(qv.z), b2f(qv.w));
    *(float4*)(kf + 4 * t) = make_float4(b2f(kv.x), b2f(kv.y), b2f(kv.z), b2f(kv.w));
    __syncthreads();
    const float scale = scale_p[0];
    float rq[4], rk[4];
#pragma unroll
    for (int u = 0; u < 4; u++) {
      int j = 4 * t + u;
      float2 cs = cs_tab[j];
      float qrot = (j < 512) ? -qf[2 * j + 1] : qf[2 * (j - 512)];
      float krot = (j < 512) ? -kf[2 * j + 1] : kf[2 * (j - 512)];
      rq[u] = qf[j] * cs.x + qrot * cs.y;
      rk[u] = kf[j] * cs.x + krot * cs.y;
    }
    float ssq = rq[0] * rq[0] + rq[1] * rq[1] + rq[2] * rq[2] + rq[3] * rq[3];
    float ssk = rk[0] * rk[0] + rk[1] * rk[1] + rk[2] * rk[2] + rk[3] * rk[3];
    for (int o = 1; o < 16; o <<= 1) { ssq += __shfl_xor(ssq, o); ssk += __shfl_xor(ssk, o); }
    float qs = scale / fmaxf(sqrtf(ssq), 1e-12f);
    float ks = scale / fmaxf(sqrtf(ssk), 1e-12f);
    ushort4 qo, ko;
    qo.x = f2b(rq[0] * qs); qo.y = f2b(rq[1] * qs); qo.z = f2b(rq[2] * qs); qo.w = f2b(rq[3] * qs);
    ko.x = f2b(rk[0] * ks); ko.y = f2b(rk[1] * ks); ko.z = f2b(rk[2] * ks); ko.w = f2b(rk[3] * ks);
    ((ushort4*)qr)[t] = qo;
    ((ushort4*)kr)[t] = ko;
  }
  if (row >= 1024) return;
  // ---- V transpose job (reads V section: untouched by the rotnorm phase) ----
  const int st = row & 31, bh = row >> 5;
  const int b = bh >> 4, h = bh & 15;
  const int s0 = st * 64;
  const int si = t >> 2, dc = t & 3;
  __syncthreads();  // LDS reuse safety (qf/kf reads done before tile writes)
  const u16* src = qkv + (size_t)(b * SS + s0 + si) * 3072 + 2048 + h * DD;
  bf16x8 v0 = *(const bf16x8*)(src + dc * 8);
  bf16x8 v1 = *(const bf16x8*)(src + (dc + 4) * 8);
#pragma unroll
  for (int u = 0; u < 8; u++) tile[(dc * 8 + u) * 72 + si] = (u16)v0[u];
#pragma unroll
  for (int u = 0; u < 8; u++) tile[((dc + 4) * 8 + u) * 72 + si] = (u16)v1[u];
  __syncthreads();
#pragma unroll
  for (int it = 0; it < 2; it++) {
    int idx = t + it * 256;
    int d = idx >> 3, ch = idx & 7;
    bf16x8 o = *(const bf16x8*)(tile + d * 72 + ch * 8);
    *(bf16x8*)(vt + (size_t)(bh * DD + d) * SS + s0 + ch * 8) = o;
  }
}

// ---------------- causal flash attention (round-11 proven version) ----------------
// QBLK=128 via 8 warps; KBLK=128. Grid (32,16): bh = blockIdx.x, qt = y<8 ? y : 23-y
// (co-resident block pairs f,f+256 share bh -> K/V L2-resident; qt sums to 15).
// SWAPPED QK^T -> lane-local softmax (+2 shfl_xor); in-register P via cross-quad shfl.
__global__ __launch_bounds__(512, 4) void k_attn(const u16* __restrict__ qkv,
                                                 const u16* __restrict__ vt,
                                                 u16* __restrict__ out) {
  __shared__ __align__(16) u16 Kt[2][128 * 72];    // K rows (d=0..63 + pad)
  __shared__ __align__(16) u16 Vt[2][64 * 136];    // V^T rows d, k=0..127 + pad
  const int bh = blockIdx.x;
  const int y = blockIdx.y;
  const int qt = (y < 8) ? y : 23 - y;             // 128-row q-tile, 0..15
  const int b = bh >> 4, h = bh & 15;
  const int t = threadIdx.x, w = t >> 6, lane = t & 63, quad = lane >> 4, l15 = lane & 15;
  const int krow = t >> 2, kq = (t & 3) * 16;  // K staging: row 0..127, 16-u16 quarter
  const int dr = t >> 3, kc8 = t & 7;          // V staging: d-row 0..63, 16-k eighth
  const int srcl = (lane & 48) + ((lane >> 4) << 2);  // 20*quad: state-holder base lane
  const int qA = ((lane >> 4) & 1) * 32 + l15;        // P-exchange src lane
  const int qB = qA + 16;
  const bool hiN = (quad >> 1) & 1;
  const u16* kn = qkv + 1024;
  f32x4 zero4 = {0.f, 0.f, 0.f, 0.f};
  const int q0 = qt * 128;

  bf16x8 qf[2];
  {
    const u16* qrow = qkv + (size_t)(b * SS + q0 + 16 * w + l15) * 3072 + h * DD;
    qf[0] = *(const bf16x8*)(qrow + quad * 8);
    qf[1] = *(const bf16x8*)(qrow + 32 + quad * 8);
  }
  f32x4 oacc[4];
  for (int n = 0; n < 4; n++) oacc[n] = zero4;
  float m_i = -1e30f, l_i = 0.f;   // per-lane: state for q-row 16w+l15

  bf16x8 kv[2], vv[2];
  // prologue: load & stage tile kt=0 into buf 0
  {
    const u16* krg = kn + (size_t)(b * SS + krow) * 3072 + h * DD + kq;
    kv[0] = *(const bf16x8*)(krg);
    kv[1] = *(const bf16x8*)(krg + 8);
    const u16* vrg = vt + (size_t)(bh * DD + dr) * SS + kc8 * 16;
    vv[0] = *(const bf16x8*)(vrg);
    vv[1] = *(const bf16x8*)(vrg + 8);
  }
  *(bf16x8*)(Kt[0] + krow * 72 + kq) = kv[0];
  *(bf16x8*)(Kt[0] + krow * 72 + kq + 8) = kv[1];
  *(bf16x8*)(Vt[0] + dr * 136 + kc8 * 16) = vv[0];
  *(bf16x8*)(Vt[0] + dr * 136 + kc8 * 16 + 8) = vv[1];
  __syncthreads();
  int cur = 0;

  for (int kt = 0; kt <= qt; kt++) {
    if (kt < qt) {  // prefetch next tile into regs; staged into buf^1 below
      const int k0n = (kt + 1) * 128;
      const u16* krg = kn + (size_t)(b * SS + k0n + krow) * 3072 + h * DD + kq;
      kv[0] = *(const bf16x8*)(krg);
      kv[1] = *(const bf16x8*)(krg + 8);
      const u16* vrg = vt + (size_t)(bh * DD + dr) * SS + k0n + kc8 * 16;
      vv[0] = *(const bf16x8*)(vrg);
      vv[1] = *(const bf16x8*)(vrg + 8);
    }
    const u16* Kc = Kt[cur];
    const u16* Vc = Vt[cur];
    // ---- swapped QK^T: A = K-group (16 k-rows), B = Q ----
    f32x4 sacc[8];
#pragma unroll
    for (int n = 0; n < 8; n++) {
      sacc[n] = zero4;
#pragma unroll
      for (int c = 0; c < 2; c++) {
        bf16x8 kfrag = *(const bf16x8*)(Kc + (n * 16 + l15) * 72 + c * 32 + quad * 8);
        sacc[n] = __builtin_amdgcn_mfma_f32_16x16x32_bf16(kfrag, qf[c], sacc[n], 0, 0, 0);
      }
    }
    if (kt == qt) {  // diagonal: mask k > q-row-in-tile; k = 16n+4quad+r, q = 16w+l15
      const int qrow = 16 * w + l15, kbase = 4 * quad;
#pragma unroll
      for (int n = 0; n < 8; n++)
#pragma unroll
        for (int r = 0; r < 4; r++)
          if (16 * n + kbase + r > qrow) sacc[n][r] = -1e30f;
    }
    // ---- lane-local softmax for q-row 16w+l15 ----
    float mx = -1e30f;
#pragma unroll
    for (int n = 0; n < 8; n++)
#pragma unroll
      for (int r = 0; r < 4; r++) mx = fmaxf(mx, sacc[n][r]);
    mx = fmaxf(mx, __shfl_xor(mx, 16));
    mx = fmaxf(mx, __shfl_xor(mx, 32));
    float mn = fmaxf(m_i, mx);
    float al = __expf(m_i - mn);
    m_i = mn;
    float rs = 0.f;
#pragma unroll
    for (int n = 0; n < 8; n++)
#pragma unroll
      for (int r = 0; r < 4; r++) {
        float p = __expf(sacc[n][r] - mn);
        sacc[n][r] = p;
        rs += p;
      }
    rs += __shfl_xor(rs, 16);
    rs += __shfl_xor(rs, 32);
    l_i = al * l_i + rs;
    // broadcast al to O-row holders (O row q = quad*4+r; state at lane 20*quad+r)
    float alr[4];
#pragma unroll
    for (int r = 0; r < 4; r++) alr[r] = __shfl(al, srcl + r);
#pragma unroll
    for (int n = 0; n < 4; n++)
#pragma unroll
      for (int r = 0; r < 4; r++) oacc[n][r] *= alr[r];
    // ---- P pack to bf16 pairs, kept in registers ----
    unsigned int pkw[8][2];
#pragma unroll
    for (int n = 0; n < 8; n++) {
      pkw[n][0] = cvt_pk_bf16(sacc[n][0], sacc[n][1]);
      pkw[n][1] = cvt_pk_bf16(sacc[n][2], sacc[n][3]);
    }
    // ---- PV: A-frag built via cross-quad shfl (no LDS P) ----
#pragma unroll
    for (int c = 0; c < 4; c++) {
      unsigned int a0 = __shfl(pkw[2 * c][0], qA);
      unsigned int a1 = __shfl(pkw[2 * c][1], qA);
      unsigned int a2 = __shfl(pkw[2 * c][0], qB);
      unsigned int a3 = __shfl(pkw[2 * c][1], qB);
      unsigned int b0 = __shfl(pkw[2 * c + 1][0], qA);
      unsigned int b1 = __shfl(pkw[2 * c + 1][1], qA);
      unsigned int b2 = __shfl(pkw[2 * c + 1][0], qB);
      unsigned int b3 = __shfl(pkw[2 * c + 1][1], qB);
      union { unsigned int u[4]; bf16x8 v8; } pf;
      pf.u[0] = hiN ? b0 : a0;
      pf.u[1] = hiN ? b1 : a1;
      pf.u[2] = hiN ? b2 : a2;
      pf.u[3] = hiN ? b3 : a3;
#pragma unroll
      for (int n = 0; n < 4; n++) {
        bf16x8 vf = *(const bf16x8*)(Vc + (n * 16 + l15) * 136 + c * 32 + quad * 8);
        oacc[n] = __builtin_amdgcn_mfma_f32_16x16x32_bf16(pf.v8, vf, oacc[n], 0, 0, 0);
      }
    }
    if (kt < qt) {  // stage prefetched tile into the other buffer (no race: buf^1)
      *(bf16x8*)(Kt[cur ^ 1] + krow * 72 + kq) = kv[0];
      *(bf16x8*)(Kt[cur ^ 1] + krow * 72 + kq + 8) = kv[1];
      *(bf16x8*)(Vt[cur ^ 1] + dr * 136 + kc8 * 16) = vv[0];
      *(bf16x8*)(Vt[cur ^ 1] + dr * 136 + kc8 * 16 + 8) = vv[1];
    }
    __syncthreads();  // single barrier: buf[cur] readers done + buf^1 staged
    cur ^= 1;
  }
  float lr[4];
#pragma unroll
  for (int r = 0; r < 4; r++) lr[r] = __shfl(l_i, srcl + r);
  for (int n = 0; n < 4; n++)
    for (int r = 0; r < 4; r++) {
      int row = q0 + 16 * w + quad * 4 + r;
      out[(size_t)(b * SS + row) * EE + h * DD + n * 16 + l15] = f2b(oacc[n][r] / lr[r]);
    }
}

extern "C" void kernel_launch(void* const* d_in, const int* in_sizes, int n_in,
                              void* d_out, int out_size, void* d_ws, size_t ws_size,
                              hipStream_t stream) {
  const float* x       = (const float*)d_in[0];
  const float* ln_w    = (const float*)d_in[1];
  const float* ln_b    = (const float*)d_in[2];
  const float* qkv_w   = (const float*)d_in[3];
  const float* qkv_b   = (const float*)d_in[4];
  const float* qk_s    = (const float*)d_in[5];
  const float* out_w   = (const float*)d_in[6];
  const float* out_b   = (const float*)d_in[7];
  const float* inv_frq = (const float*)d_in[8];

  // ws (33.55 MB): xn bf16 [8.39 MB] | qkv bf16 [25.17 MB]
  u16* ws   = (u16*)d_ws;
  u16* xn   = ws;                               // 4096*1024 (LN out, later attn out)
  u16* qkv  = ws + (size_t)4096 * 1024;         // 4096*3072 (q,k normalized in place)
  // d_out is fp32 [16.78 MB]; stage bf16 scratch inside it while it's dead:
  u16* wq_b = (u16*)d_out;                      // [0, 6.29 MB): bf16 qkv_w
  float2* cs_tab = (float2*)((char*)d_out + 6291456);  // [6.29, 6.30 MB): cos/sin table
  u16* vt   = (u16*)d_out + (size_t)4194304;    // [8.39, 16.78 MB): bf16 V^T

  k_prep<<<7172, 256, 0, stream>>>(qkv_w, wq_b, inv_frq, cs_tab, x, ln_w, ln_b, xn);
  k_gemm_b<<<dim3(24, 32), 256, 0, stream>>>(xn, wq_b, qkv_b, qkv, 4096, 3072, 1024);
  k_rotv<<<4096, 256, 0, stream>>>(qkv, cs_tab, qk_s, vt);
  k_attn<<<dim3(32, 16), 512, 0, stream>>>(qkv, vt, xn);
  k_gemm_fw<<<dim3(8, 64), 256, 0, stream>>>(xn, out_w, out_b, (float*)d_out, 4096, 1024, 1024);
}

// Round 17
// 212.507 us; speedup vs baseline: 1.0993x; 1.0007x over previous
//
#include <hip/hip_runtime.h>

typedef unsigned short u16;
typedef __attribute__((ext_vector_type(8))) short bf16x8;   // 8 bf16 in 4 VGPRs (MFMA A/B frag)
typedef __attribute__((ext_vector_type(4))) float f32x4;    // MFMA C/D frag

#define SS 2048
#define EE 1024
#define HH 16
#define DD 64

__device__ __forceinline__ float b2f(u16 u) {
  union { unsigned int i; float f; } v; v.i = ((unsigned int)u) << 16; return v.f;
}
__device__ __forceinline__ u16 f2b(float f) {
  union { float f; unsigned int i; } v; v.f = f;
  unsigned int i = v.i;
  return (u16)((i + 0x7FFFu + ((i >> 16) & 1u)) >> 16);  // RNE
}
__device__ __forceinline__ unsigned int cvt_pk_bf16(float lo, float hi) {
  unsigned int r;
  asm("v_cvt_pk_bf16_f32 %0, %1, %2" : "=v"(r) : "v"(lo), "v"(hi));  // RNE pack, low=lo
  return r;
}

// async global->LDS, 16B per lane (m97 pattern; LDS dest = wave-uniform base + lane*16)
#define GLD16(g, l)                                                         \
  __builtin_amdgcn_global_load_lds(                                         \
      (const __attribute__((address_space(1))) unsigned int*)(g),           \
      (__attribute__((address_space(3))) unsigned int*)(l), 16, 0, 0)

// ---------------- fused prep: trig table | LayerNorm (qkv_w cvt REMOVED) ----------------
// blocks [0,4): cos/sin table; [4,4100): LN rows
__global__ __launch_bounds__(256) void k_prep(const float* __restrict__ inv_freq,
                                              float2* __restrict__ cs,
                                              const float* __restrict__ x,
                                              const float* __restrict__ lw,
                                              const float* __restrict__ lb,
                                              u16* __restrict__ xn) {
  const int bx = blockIdx.x, t = threadIdx.x;
  if (bx < 4) {
    const int i = bx * 256 + t;
    float th = 2048.0f * inv_freq[i];
    cs[i] = make_float2(cosf(th), sinf(th));
    return;
  }
  const int row = bx - 4;
  float4 v = ((const float4*)(x + (size_t)row * EE))[t];
  float f0 = v.x, f1 = v.y, f2 = v.z, f3 = v.w;
  float s = f0 + f1 + f2 + f3;
  float ss = f0 * f0 + f1 * f1 + f2 * f2 + f3 * f3;
  for (int o = 1; o < 64; o <<= 1) { s += __shfl_xor(s, o); ss += __shfl_xor(ss, o); }
  __shared__ float red[8];
  int w = t >> 6;
  if ((t & 63) == 0) { red[w] = s; red[4 + w] = ss; }
  __syncthreads();
  s = red[0] + red[1] + red[2] + red[3];
  ss = red[4] + red[5] + red[6] + red[7];
  float mu = s * (1.0f / 1024.0f);
  float var = ss * (1.0f / 1024.0f) - mu * mu;
  float rstd = rsqrtf(var + 1e-5f);
  float4 wv = ((const float4*)lw)[t];
  float4 bv = ((const float4*)lb)[t];
  ushort4 o;
  o.x = f2b((f0 - mu) * rstd * wv.x + bv.x);
  o.y = f2b((f1 - mu) * rstd * wv.y + bv.y);
  o.z = f2b((f2 - mu) * rstd * wv.z + bv.z);
  o.w = f2b((f3 - mu) * rstd * wv.w + bv.w);
  ((ushort4*)(xn + (size_t)row * EE))[t] = o;
}

// ---- MFMA GEMM  C[M,N] = A[M,K](bf16) * W[N,K]^T(fp32, converted in-flight) + bias ----
// 128x128 tile; A via GLD16 dbuf; W fp32 reg-prefetch -> cvt_pk -> linear b128
// ds_write into buf^1 after MFMA (gemm_fw-proven). 1 barrier/iter. Replaces the
// separate qkv_w cvt pass (saves 12.6 MB HBM round-trip + 3072 prep blocks).
__global__ __launch_bounds__(256) void k_gemm_b(const u16* __restrict__ A,
                                                const float* __restrict__ W,
                                                const float* __restrict__ bias,
                                                u16* __restrict__ C,
                                                int M, int N, int K) {
  __shared__ __align__(16) u16 As[2][128 * 32];   // 16 KB
  __shared__ __align__(16) u16 Ws[2][128 * 32];   // 16 KB
  const int t = threadIdx.x;
  const int m0 = blockIdx.y * 128, n0 = blockIdx.x * 128;
  const int lane = t & 63, w = t >> 6, quad = lane >> 4, l15 = lane & 15;
  const int wm = (w & 1) * 64, wn = (w >> 1) * 64;

  f32x4 zero4 = {0.f, 0.f, 0.f, 0.f};
  f32x4 acc[4][4];
  for (int mi = 0; mi < 4; mi++)
    for (int ni = 0; ni < 4; ni++) acc[mi][ni] = zero4;

  const u16* Ag = A + (size_t)(m0 + (t >> 2)) * K + (t & 3) * 8;
  const float* Wg0 = W + (size_t)(n0 + (t >> 2)) * K + (t & 3) * 8;
  const float* Wg1 = Wg0 + (size_t)64 * K;
  const size_t rowskip = (size_t)64 * K;

  // prologue: k=0 staged into buf 0
  float4 wa = *(const float4*)(Wg0);
  float4 wb = *(const float4*)(Wg0 + 4);
  float4 wc = *(const float4*)(Wg1);
  float4 wd = *(const float4*)(Wg1 + 4);
  GLD16(Ag, As[0] + t * 8);
  GLD16(Ag + rowskip, As[0] + 2048 + t * 8);
  {
    union { unsigned int u[4]; bf16x8 v8; } p0, p1;
    p0.u[0] = cvt_pk_bf16(wa.x, wa.y); p0.u[1] = cvt_pk_bf16(wa.z, wa.w);
    p0.u[2] = cvt_pk_bf16(wb.x, wb.y); p0.u[3] = cvt_pk_bf16(wb.z, wb.w);
    p1.u[0] = cvt_pk_bf16(wc.x, wc.y); p1.u[1] = cvt_pk_bf16(wc.z, wc.w);
    p1.u[2] = cvt_pk_bf16(wd.x, wd.y); p1.u[3] = cvt_pk_bf16(wd.z, wd.w);
    *(bf16x8*)(Ws[0] + t * 8) = p0.v8;          // rows 0..63, linear layout
    *(bf16x8*)(Ws[0] + 2048 + t * 8) = p1.v8;   // rows 64..127
  }
  __syncthreads();
  int cur = 0;

  for (int k0 = 0; k0 < K; k0 += 32) {
    const bool pref = (k0 + 32 < K);
    if (pref) {  // issue next tile's loads early (latency hidden under MFMA)
      GLD16(Ag + k0 + 32, As[cur ^ 1] + t * 8);
      GLD16(Ag + rowskip + k0 + 32, As[cur ^ 1] + 2048 + t * 8);
      wa = *(const float4*)(Wg0 + k0 + 32);
      wb = *(const float4*)(Wg0 + k0 + 36);
      wc = *(const float4*)(Wg1 + k0 + 32);
      wd = *(const float4*)(Wg1 + k0 + 36);
    }
    bf16x8 af[4], wf[4];
#pragma unroll
    for (int i = 0; i < 4; i++) {
      af[i] = *(const bf16x8*)(As[cur] + (wm + i * 16 + l15) * 32 + quad * 8);
      wf[i] = *(const bf16x8*)(Ws[cur] + (wn + i * 16 + l15) * 32 + quad * 8);
    }
#pragma unroll
    for (int mi = 0; mi < 4; mi++)
#pragma unroll
      for (int ni = 0; ni < 4; ni++)
        acc[mi][ni] = __builtin_amdgcn_mfma_f32_16x16x32_bf16(af[mi], wf[ni], acc[mi][ni], 0, 0, 0);
    if (pref) {  // convert + stage W(k+1) into buf^1 (disjoint from buf[cur] readers)
      union { unsigned int u[4]; bf16x8 v8; } p0, p1;
      p0.u[0] = cvt_pk_bf16(wa.x, wa.y); p0.u[1] = cvt_pk_bf16(wa.z, wa.w);
      p0.u[2] = cvt_pk_bf16(wb.x, wb.y); p0.u[3] = cvt_pk_bf16(wb.z, wb.w);
      p1.u[0] = cvt_pk_bf16(wc.x, wc.y); p1.u[1] = cvt_pk_bf16(wc.z, wc.w);
      p1.u[2] = cvt_pk_bf16(wd.x, wd.y); p1.u[3] = cvt_pk_bf16(wd.z, wd.w);
      *(bf16x8*)(Ws[cur ^ 1] + t * 8) = p0.v8;
      *(bf16x8*)(Ws[cur ^ 1] + 2048 + t * 8) = p1.v8;
    }
    __syncthreads();  // drains A prefetch + all reads of buf[cur] done
    cur ^= 1;
  }
  for (int mi = 0; mi < 4; mi++)
    for (int ni = 0; ni < 4; ni++) {
      int col = n0 + wn + ni * 16 + l15;
      float bb = bias[col];
      for (int r = 0; r < 4; r++) {
        int grow = m0 + wm + mi * 16 + quad * 4 + r;
        C[(size_t)grow * N + col] = f2b(acc[mi][ni][r] + bb);
      }
    }
}

// ---- MFMA GEMM with fp32 W (converted in-flight) ----
// dbuf + prefetch-before-compute: As via GLD16 dbuf; W fp32 reg-prefetch,
// cvt_pk + ds_write into Ws[buf^1] after this iter's MFMA. 1 barrier/iter.
__global__ __launch_bounds__(256) void k_gemm_fw(const u16* __restrict__ A,
                                                 const float* __restrict__ W,
                                                 const float* __restrict__ bias,
                                                 float* __restrict__ C,
                                                 int M, int N, int K) {
  __shared__ __align__(16) u16 As[2][64 * 32];    // 8 KB
  __shared__ __align__(16) u16 Ws[2][128 * 32];   // 16 KB
  const int t = threadIdx.x;
  const int m0 = blockIdx.y * 64, n0 = blockIdx.x * 128;
  const int lane = t & 63, w = t >> 6, quad = lane >> 4, l15 = lane & 15;
  const int wm = (w & 1) * 32, wn = (w >> 1) * 64;

  f32x4 zero4 = {0.f, 0.f, 0.f, 0.f};
  f32x4 acc[2][4];
  for (int mi = 0; mi < 2; mi++)
    for (int ni = 0; ni < 4; ni++) acc[mi][ni] = zero4;

  const u16* Ag = A + (size_t)(m0 + (t >> 2)) * K + (t & 3) * 8;
  const float* Wg0 = W + (size_t)(n0 + (t >> 2)) * K + (t & 3) * 8;
  const float* Wg1 = Wg0 + (size_t)64 * K;

  // prologue: k=0 staged into buf 0
  float4 wa = *(const float4*)(Wg0);
  float4 wb = *(const float4*)(Wg0 + 4);
  float4 wc = *(const float4*)(Wg1);
  float4 wd = *(const float4*)(Wg1 + 4);
  GLD16(Ag, As[0] + t * 8);
  {
    union { unsigned int u[4]; bf16x8 v8; } p0, p1;
    p0.u[0] = cvt_pk_bf16(wa.x, wa.y); p0.u[1] = cvt_pk_bf16(wa.z, wa.w);
    p0.u[2] = cvt_pk_bf16(wb.x, wb.y); p0.u[3] = cvt_pk_bf16(wb.z, wb.w);
    p1.u[0] = cvt_pk_bf16(wc.x, wc.y); p1.u[1] = cvt_pk_bf16(wc.z, wc.w);
    p1.u[2] = cvt_pk_bf16(wd.x, wd.y); p1.u[3] = cvt_pk_bf16(wd.z, wd.w);
    *(bf16x8*)(Ws[0] + t * 8) = p0.v8;
    *(bf16x8*)(Ws[0] + 2048 + t * 8) = p1.v8;
  }
  __syncthreads();
  int cur = 0;

  for (int k0 = 0; k0 < K; k0 += 32) {
    const bool pref = (k0 + 32 < K);
    if (pref) {  // issue next tile's loads early (latency hidden under MFMA)
      GLD16(Ag + k0 + 32, As[cur ^ 1] + t * 8);
      wa = *(const float4*)(Wg0 + k0 + 32);
      wb = *(const float4*)(Wg0 + k0 + 36);
      wc = *(const float4*)(Wg1 + k0 + 32);
      wd = *(const float4*)(Wg1 + k0 + 36);
    }
    bf16x8 af[2], wf[4];
#pragma unroll
    for (int i = 0; i < 2; i++)
      af[i] = *(const bf16x8*)(As[cur] + (wm + i * 16 + l15) * 32 + quad * 8);
#pragma unroll
    for (int i = 0; i < 4; i++)
      wf[i] = *(const bf16x8*)(Ws[cur] + (wn + i * 16 + l15) * 32 + quad * 8);
#pragma unroll
    for (int mi = 0; mi < 2; mi++)
#pragma unroll
      for (int ni = 0; ni < 4; ni++)
        acc[mi][ni] = __builtin_amdgcn_mfma_f32_16x16x32_bf16(af[mi], wf[ni], acc[mi][ni], 0, 0, 0);
    if (pref) {  // convert + stage W(k+1) into buf^1 (disjoint from buf[cur] readers)
      union { unsigned int u[4]; bf16x8 v8; } p0, p1;
      p0.u[0] = cvt_pk_bf16(wa.x, wa.y); p0.u[1] = cvt_pk_bf16(wa.z, wa.w);
      p0.u[2] = cvt_pk_bf16(wb.x, wb.y); p0.u[3] = cvt_pk_bf16(wb.z, wb.w);
      p1.u[0] = cvt_pk_bf16(wc.x, wc.y); p1.u[1] = cvt_pk_bf16(wc.z, wc.w);
      p1.u[2] = cvt_pk_bf16(wd.x, wd.y); p1.u[3] = cvt_pk_bf16(wd.z, wd.w);
      *(bf16x8*)(Ws[cur ^ 1] + t * 8) = p0.v8;
      *(bf16x8*)(Ws[cur ^ 1] + 2048 + t * 8) = p1.v8;
    }
    __syncthreads();
    cur ^= 1;
  }
  for (int mi = 0; mi < 2; mi++)
    for (int ni = 0; ni < 4; ni++) {
      int col = n0 + wn + ni * 16 + l15;
      float bb = bias[col];
      for (int r = 0; r < 4; r++) {
        int grow = m0 + wm + mi * 16 + quad * 4 + r;
        C[(size_t)grow * N + col] = acc[mi][ni][r] + bb;
      }
    }
}

// ------ fused: rotate+l2norm+scale (all 4096 rows) | V transpose (blocks < 1024) ------
// (round-11 proven version)
__global__ __launch_bounds__(256) void k_rotv(u16* __restrict__ qkv,
                                              const float2* __restrict__ cs_tab,
                                              const float* __restrict__ scale_p,
                                              u16* __restrict__ vt) {
  __shared__ float qf[1024];
  __shared__ float kf[1024];
  __shared__ __align__(16) u16 tile[64 * 72];
  const int row = blockIdx.x, t = threadIdx.x;
  {
    u16* qr = qkv + (size_t)row * 3072;
    u16* kr = qr + 1024;
    ushort4 qv = ((const ushort4*)qr)[t];
    ushort4 kv = ((const ushort4*)kr)[t];
    *(float4*)(qf + 4 * t) = make_float4(b2f(qv.x), b2f(qv.y), b2f(qv.z), b2f(qv.w));
    *(float4*)(kf + 4 * t) = make_float4(b2f(kv.x), b2f(kv.y), b2f(kv.z), b2f(kv.w));
    __syncthreads();
    const float scale = scale_p[0];
    float rq[4], rk[4];
#pragma unroll
    for (int u = 0; u < 4; u++) {
      int j = 4 * t + u;
      float2 cs = cs_tab[j];
      float qrot = (j < 512) ? -qf[2 * j + 1] : qf[2 * (j - 512)];
      float krot = (j < 512) ? -kf[2 * j + 1] : kf[2 * (j - 512)];
      rq[u] = qf[j] * cs.x + qrot * cs.y;
      rk[u] = kf[j] * cs.x + krot * cs.y;
    }
    float ssq = rq[0] * rq[0] + rq[1] * rq[1] + rq[2] * rq[2] + rq[3] * rq[3];
    float ssk = rk[0] * rk[0] + rk[1] * rk[1] + rk[2] * rk[2] + rk[3] * rk[3];
    for (int o = 1; o < 16; o <<= 1) { ssq += __shfl_xor(ssq, o); ssk += __shfl_xor(ssk, o); }
    float qs = scale / fmaxf(sqrtf(ssq), 1e-12f);
    float ks = scale / fmaxf(sqrtf(ssk), 1e-12f);
    ushort4 qo, ko;
    qo.x = f2b(rq[0] * qs); qo.y = f2b(rq[1] * qs); qo.z = f2b(rq[2] * qs); qo.w = f2b(rq[3] * qs);
    ko.x = f2b(rk[0] * ks); ko.y = f2b(rk[1] * ks); ko.z = f2b(rk[2] * ks); ko.w = f2b(rk[3] * ks);
    ((ushort4*)qr)[t] = qo;
    ((ushort4*)kr)[t] = ko;
  }
  if (row >= 1024) return;
  // ---- V transpose job (reads V section: untouched by the rotnorm phase) ----
  const int st = row & 31, bh = row >> 5;
  const int b = bh >> 4, h = bh & 15;
  const int s0 = st * 64;
  const int si = t >> 2, dc = t & 3;
  __syncthreads();  // LDS reuse safety (qf/kf reads done before tile writes)
  const u16* src = qkv + (size_t)(b * SS + s0 + si) * 3072 + 2048 + h * DD;
  bf16x8 v0 = *(const bf16x8*)(src + dc * 8);
  bf16x8 v1 = *(const bf16x8*)(src + (dc + 4) * 8);
#pragma unroll
  for (int u = 0; u < 8; u++) tile[(dc * 8 + u) * 72 + si] = (u16)v0[u];
#pragma unroll
  for (int u = 0; u < 8; u++) tile[((dc + 4) * 8 + u) * 72 + si] = (u16)v1[u];
  __syncthreads();
#pragma unroll
  for (int it = 0; it < 2; it++) {
    int idx = t + it * 256;
    int d = idx >> 3, ch = idx & 7;
    bf16x8 o = *(const bf16x8*)(tile + d * 72 + ch * 8);
    *(bf16x8*)(vt + (size_t)(bh * DD + d) * SS + s0 + ch * 8) = o;
  }
}

// ---------------- causal flash attention (round-11 proven version) ----------------
// QBLK=128 via 8 warps; KBLK=128. Grid (32,16): bh = blockIdx.x, qt = y<8 ? y : 23-y
// (co-resident block pairs f,f+256 share bh -> K/V L2-resident; qt sums to 15).
// SWAPPED QK^T -> lane-local softmax (+2 shfl_xor); in-register P via cross-quad shfl.
__global__ __launch_bounds__(512, 4) void k_attn(const u16* __restrict__ qkv,
                                                 const u16* __restrict__ vt,
                                                 u16* __restrict__ out) {
  __shared__ __align__(16) u16 Kt[2][128 * 72];    // K rows (d=0..63 + pad)
  __shared__ __align__(16) u16 Vt[2][64 * 136];    // V^T rows d, k=0..127 + pad
  const int bh = blockIdx.x;
  const int y = blockIdx.y;
  const int qt = (y < 8) ? y : 23 - y;             // 128-row q-tile, 0..15
  const int b = bh >> 4, h = bh & 15;
  const int t = threadIdx.x, w = t >> 6, lane = t & 63, quad = lane >> 4, l15 = lane & 15;
  const int krow = t >> 2, kq = (t & 3) * 16;  // K staging: row 0..127, 16-u16 quarter
  const int dr = t >> 3, kc8 = t & 7;          // V staging: d-row 0..63, 16-k eighth
  const int srcl = (lane & 48) + ((lane >> 4) << 2);  // 20*quad: state-holder base lane
  const int qA = ((lane >> 4) & 1) * 32 + l15;        // P-exchange src lane
  const int qB = qA + 16;
  const bool hiN = (quad >> 1) & 1;
  const u16* kn = qkv + 1024;
  f32x4 zero4 = {0.f, 0.f, 0.f, 0.f};
  const int q0 = qt * 128;

  bf16x8 qf[2];
  {
    const u16* qrow = qkv + (size_t)(b * SS + q0 + 16 * w + l15) * 3072 + h * DD;
    qf[0] = *(const bf16x8*)(qrow + quad * 8);
    qf[1] = *(const bf16x8*)(qrow + 32 + quad * 8);
  }
  f32x4 oacc[4];
  for (int n = 0; n < 4; n++) oacc[n] = zero4;
  float m_i = -1e30f, l_i = 0.f;   // per-lane: state for q-row 16w+l15

  bf16x8 kv[2], vv[2];
  // prologue: load & stage tile kt=0 into buf 0
  {
    const u16* krg = kn + (size_t)(b * SS + krow) * 3072 + h * DD + kq;
    kv[0] = *(const bf16x8*)(krg);
    kv[1] = *(const bf16x8*)(krg + 8);
    const u16* vrg = vt + (size_t)(bh * DD + dr) * SS + kc8 * 16;
    vv[0] = *(const bf16x8*)(vrg);
    vv[1] = *(const bf16x8*)(vrg + 8);
  }
  *(bf16x8*)(Kt[0] + krow * 72 + kq) = kv[0];
  *(bf16x8*)(Kt[0] + krow * 72 + kq + 8) = kv[1];
  *(bf16x8*)(Vt[0] + dr * 136 + kc8 * 16) = vv[0];
  *(bf16x8*)(Vt[0] + dr * 136 + kc8 * 16 + 8) = vv[1];
  __syncthreads();
  int cur = 0;

  for (int kt = 0; kt <= qt; kt++) {
    if (kt < qt) {  // prefetch next tile into regs; staged into buf^1 below
      const int k0n = (kt + 1) * 128;
      const u16* krg = kn + (size_t)(b * SS + k0n + krow) * 3072 + h * DD + kq;
      kv[0] = *(const bf16x8*)(krg);
      kv[1] = *(const bf16x8*)(krg + 8);
      const u16* vrg = vt + (size_t)(bh * DD + dr) * SS + k0n + kc8 * 16;
      vv[0] = *(const bf16x8*)(vrg);
      vv[1] = *(const bf16x8*)(vrg + 8);
    }
    const u16* Kc = Kt[cur];
    const u16* Vc = Vt[cur];
    // ---- swapped QK^T: A = K-group (16 k-rows), B = Q ----
    f32x4 sacc[8];
#pragma unroll
    for (int n = 0; n < 8; n++) {
      sacc[n] = zero4;
#pragma unroll
      for (int c = 0; c < 2; c++) {
        bf16x8 kfrag = *(const bf16x8*)(Kc + (n * 16 + l15) * 72 + c * 32 + quad * 8);
        sacc[n] = __builtin_amdgcn_mfma_f32_16x16x32_bf16(kfrag, qf[c], sacc[n], 0, 0, 0);
      }
    }
    if (kt == qt) {  // diagonal: mask k > q-row-in-tile; k = 16n+4quad+r, q = 16w+l15
      const int qrow = 16 * w + l15, kbase = 4 * quad;
#pragma unroll
      for (int n = 0; n < 8; n++)
#pragma unroll
        for (int r = 0; r < 4; r++)
          if (16 * n + kbase + r > qrow) sacc[n][r] = -1e30f;
    }
    // ---- lane-local softmax for q-row 16w+l15 ----
    float mx = -1e30f;
#pragma unroll
    for (int n = 0; n < 8; n++)
#pragma unroll
      for (int r = 0; r < 4; r++) mx = fmaxf(mx, sacc[n][r]);
    mx = fmaxf(mx, __shfl_xor(mx, 16));
    mx = fmaxf(mx, __shfl_xor(mx, 32));
    float mn = fmaxf(m_i, mx);
    float al = __expf(m_i - mn);
    m_i = mn;
    float rs = 0.f;
#pragma unroll
    for (int n = 0; n < 8; n++)
#pragma unroll
      for (int r = 0; r < 4; r++) {
        float p = __expf(sacc[n][r] - mn);
        sacc[n][r] = p;
        rs += p;
      }
    rs += __shfl_xor(rs, 16);
    rs += __shfl_xor(rs, 32);
    l_i = al * l_i + rs;
    // broadcast al to O-row holders (O row q = quad*4+r; state at lane 20*quad+r)
    float alr[4];
#pragma unroll
    for (int r = 0; r < 4; r++) alr[r] = __shfl(al, srcl + r);
#pragma unroll
    for (int n = 0; n < 4; n++)
#pragma unroll
      for (int r = 0; r < 4; r++) oacc[n][r] *= alr[r];
    // ---- P pack to bf16 pairs, kept in registers ----
    unsigned int pkw[8][2];
#pragma unroll
    for (int n = 0; n < 8; n++) {
      pkw[n][0] = cvt_pk_bf16(sacc[n][0], sacc[n][1]);
      pkw[n][1] = cvt_pk_bf16(sacc[n][2], sacc[n][3]);
    }
    // ---- PV: A-frag built via cross-quad shfl (no LDS P) ----
#pragma unroll
    for (int c = 0; c < 4; c++) {
      unsigned int a0 = __shfl(pkw[2 * c][0], qA);
      unsigned int a1 = __shfl(pkw[2 * c][1], qA);
      unsigned int a2 = __shfl(pkw[2 * c][0], qB);
      unsigned int a3 = __shfl(pkw[2 * c][1], qB);
      unsigned int b0 = __shfl(pkw[2 * c + 1][0], qA);
      unsigned int b1 = __shfl(pkw[2 * c + 1][1], qA);
      unsigned int b2 = __shfl(pkw[2 * c + 1][0], qB);
      unsigned int b3 = __shfl(pkw[2 * c + 1][1], qB);
      union { unsigned int u[4]; bf16x8 v8; } pf;
      pf.u[0] = hiN ? b0 : a0;
      pf.u[1] = hiN ? b1 : a1;
      pf.u[2] = hiN ? b2 : a2;
      pf.u[3] = hiN ? b3 : a3;
#pragma unroll
      for (int n = 0; n < 4; n++) {
        bf16x8 vf = *(const bf16x8*)(Vc + (n * 16 + l15) * 136 + c * 32 + quad * 8);
        oacc[n] = __builtin_amdgcn_mfma_f32_16x16x32_bf16(pf.v8, vf, oacc[n], 0, 0, 0);
      }
    }
    if (kt < qt) {  // stage prefetched tile into the other buffer (no race: buf^1)
      *(bf16x8*)(Kt[cur ^ 1] + krow * 72 + kq) = kv[0];
      *(bf16x8*)(Kt[cur ^ 1] + krow * 72 + kq + 8) = kv[1];
      *(bf16x8*)(Vt[cur ^ 1] + dr * 136 + kc8 * 16) = vv[0];
      *(bf16x8*)(Vt[cur ^ 1] + dr * 136 + kc8 * 16 + 8) = vv[1];
    }
    __syncthreads();  // single barrier: buf[cur] readers done + buf^1 staged
    cur ^= 1;
  }
  float lr[4];
#pragma unroll
  for (int r = 0; r < 4; r++) lr[r] = __shfl(l_i, srcl + r);
  for (int n = 0; n < 4; n++)
    for (int r = 0; r < 4; r++) {
      int row = q0 + 16 * w + quad * 4 + r;
      out[(size_t)(b * SS + row) * EE + h * DD + n * 16 + l15] = f2b(oacc[n][r] / lr[r]);
    }
}

extern "C" void kernel_launch(void* const* d_in, const int* in_sizes, int n_in,
                              void* d_out, int out_size, void* d_ws, size_t ws_size,
                              hipStream_t stream) {
  const float* x       = (const float*)d_in[0];
  const float* ln_w    = (const float*)d_in[1];
  const float* ln_b    = (const float*)d_in[2];
  const float* qkv_w   = (const float*)d_in[3];
  const float* qkv_b   = (const float*)d_in[4];
  const float* qk_s    = (const float*)d_in[5];
  const float* out_w   = (const float*)d_in[6];
  const float* out_b   = (const float*)d_in[7];
  const float* inv_frq = (const float*)d_in[8];

  // ws (33.55 MB): xn bf16 [8.39 MB] | qkv bf16 [25.17 MB]
  u16* ws   = (u16*)d_ws;
  u16* xn   = ws;                               // 4096*1024 (LN out, later attn out)
  u16* qkv  = ws + (size_t)4096 * 1024;         // 4096*3072 (q,k normalized in place)
  // d_out is fp32 [16.78 MB]; stage scratch inside it while it's dead:
  float2* cs_tab = (float2*)((char*)d_out + 6291456);  // [6.29, 6.30 MB): cos/sin table
  u16* vt   = (u16*)d_out + (size_t)4194304;    // [8.39, 16.78 MB): bf16 V^T

  k_prep<<<4100, 256, 0, stream>>>(inv_frq, cs_tab, x, ln_w, ln_b, xn);
  k_gemm_b<<<dim3(24, 32), 256, 0, stream>>>(xn, qkv_w, qkv_b, qkv, 4096, 3072, 1024);
  k_rotv<<<4096, 256, 0, stream>>>(qkv, cs_tab, qk_s, vt);
  k_attn<<<dim3(32, 16), 512, 0, stream>>>(qkv, vt, xn);
  k_gemm_fw<<<dim3(8, 64), 256, 0, stream>>>(xn, out_w, out_b, (float*)d_out, 4096, 1024, 1024);
}